// Round 14
// baseline (399.540 us; speedup 1.0000x reference)
//
#include <hip/hip_runtime.h>
#include <math.h>

typedef unsigned short u16;
typedef unsigned int uint;
typedef __attribute__((ext_vector_type(8))) short bh8;   // 8 bf16 in 4 VGPRs
typedef __attribute__((ext_vector_type(4))) float f32x4;

#define DEV __device__ __forceinline__

DEV u16 f2bf(float x) {                       // fp32 -> bf16 RNE
  uint u = __builtin_bit_cast(uint, x);
  return (u16)((u + 0x7FFFu + ((u >> 16) & 1u)) >> 16);
}
DEV float bf2f(u16 h) { return __builtin_bit_cast(float, (uint)h << 16); }

// Bijective XCD-aware swizzle: 8 XCDs, contiguous chunk per XCD.
DEV int xcd_swz(int bid, int nb) {
  int c = nb >> 3;
  return (bid & 7) * c + (bid >> 3);
}

// ===========================================================================
// ENCODER stage 1: conv1 fp32 VALU implicit-GEMM (exact numerics).
// BM=64 x BN=64 tile, acc[4][4] (16 VGPR) -> no scratch spills.
// Emits h1 as packed-uint (hi|lo bf16) parity-split NCHW planes:
//   h1u[(n*128+oc)*16384 + ih*128 + (iw&1)*64 + (iw>>1)]
// ===========================================================================
__global__ __launch_bounds__(256, 4) void conv1_f32(const float* __restrict__ src,
                                                    const float* __restrict__ Bt,
                                                    const float* __restrict__ bias,
                                                    uint* __restrict__ outu) {
  __shared__ __align__(16) float As[16*64];
  __shared__ __align__(16) float Bs[16*64];

  const int t = threadIdx.x;
  const int bid = (int)blockIdx.x;
  const int nt = bid & 1, m = bid >> 1;      // m in [0,2048): (n, h, whalf)
  const int pl = t & 63, kb = t >> 6;        // kb 0..3
  const int p = m*64 + pl;
  const int n = p >> 14, h = (p >> 7) & 127, w = p & 127;
  const int ti = t & 15, tj = t >> 4;

  float acc[4][4];
  #pragma unroll
  for (int i = 0; i < 4; ++i)
    #pragma unroll
    for (int j = 0; j < 4; ++j) acc[i][j] = 0.f;

  for (int k0 = 0; k0 < 48; k0 += 16) {
    #pragma unroll
    for (int jj = 0; jj < 4; ++jj) {
      int kr = jj*4 + kb, k = k0 + kr;
      int ic = k >> 4, r = k & 15;
      int ih = 2*h - 1 + (r >> 2), iw = 2*w - 1 + (r & 3);
      As[kr*64 + pl] = ((unsigned)ih < 256u && (unsigned)iw < 256u)
        ? src[((n*3 + ic) << 16) + (ih << 8) + iw] : 0.f;
    }
    {
      int kr = t >> 4, c4 = t & 15;          // 16 rows x 16 float4
      ((float4*)Bs)[kr*16 + c4] =
          *((const float4*)(Bt + (size_t)(k0 + kr)*128 + nt*64) + c4);
    }
    __syncthreads();
    #pragma unroll
    for (int kk = 0; kk < 16; ++kk) {
      float a[4], b[4];
      *(float4*)&a[0] = *(const float4*)&As[kk*64 + ti*4];
      *(float4*)&b[0] = *(const float4*)&Bs[kk*64 + tj*4];
      #pragma unroll
      for (int i = 0; i < 4; ++i)
        #pragma unroll
        for (int j = 0; j < 4; ++j)
          acc[i][j] += a[i]*b[j];
    }
    __syncthreads();
  }

  // packed hi/lo epilogue (pixels w = woff + ti*4 + q)
  const int nn = m >> 8, hh = (m >> 1) & 127;
  const int woff2 = (m & 1) * 32;            // woff/2 in uints
  #pragma unroll
  for (int j = 0; j < 4; ++j) {
    const int oc = nt*64 + tj*4 + j;
    uint pk[4];
    #pragma unroll
    for (int q = 0; q < 4; ++q) {
      float v = fmaxf(acc[q][j] + bias[oc], 0.f);
      u16 hi = f2bf(v);
      u16 lo = f2bf(v - bf2f(hi));
      pk[q] = (uint)hi | ((uint)lo << 16);
    }
    uint* bp = outu + (size_t)(nn*128 + oc)*16384 + hh*128;
    *(uint2*)(bp + woff2 + ti*2)      = make_uint2(pk[0], pk[2]);
    *(uint2*)(bp + 64 + woff2 + ti*2) = make_uint2(pk[1], pk[3]);
  }
}

// ===========================================================================
// ENCODER stage 2: conv2 bf16x3 split MFMA. BM=128, BN=128, BK=64, grid 512.
// Same k-order as BK=32 version (bit-identical sums), half the barriers.
// ===========================================================================
__global__ __launch_bounds__(256, 2) void conv2_mfma3(const uint* __restrict__ h1u,
                                                      const u16* __restrict__ Bh,
                                                      const u16* __restrict__ Bl,
                                                      const float* __restrict__ bias,
                                                      float* __restrict__ out) {
  __shared__ __align__(16) u16 Ah[128*72 + 32];
  __shared__ __align__(16) u16 Al[128*72 + 32];
  __shared__ __align__(16) u16 Bhs[128*72 + 32];
  __shared__ __align__(16) u16 Bls[128*72 + 32];

  const int t = threadIdx.x;
  const int bid = xcd_swz((int)blockIdx.x, (int)gridDim.x);
  const int nt = bid & 1, mt = bid >> 1;
  const int pl = t & 127, kb = t >> 7;
  const int p = mt*128 + pl;
  const int n = p >> 12, h = (p >> 6) & 63, w = p & 63;
  const int lane = t & 63, wv = t >> 6;
  const int lr = lane & 15, lg = lane >> 4;
  const int wm = wv & 1, wn = wv >> 1;

  int off[4]; uint mskd[4];
  off[0] = 64 + w - 1; mskd[0] = (w >= 1)  ? ~0u : 0u;
  off[1] = w;          mskd[1] = ~0u;
  off[2] = 64 + w;     mskd[2] = ~0u;
  off[3] = w + 1;      mskd[3] = (w <= 62) ? ~0u : 0u;

  f32x4 acc[4][4];
  #pragma unroll
  for (int fm = 0; fm < 4; ++fm)
    #pragma unroll
    for (int fn = 0; fn < 4; ++fn)
      #pragma unroll
      for (int q = 0; q < 4; ++q) acc[fm][fn][q] = 0.f;

  const int aw = pl*72 + kb*32;

  for (int k0 = 0; k0 < 2048; k0 += 64) {
    const int dy = k0 >> 9, icb = (k0 >> 2) & 127;   // ic block of 16 (8 per kb)
    const int ih = 2*h - 1 + dy;
    const uint mih = ((unsigned)ih < 128u) ? ~0u : 0u;
    const uint* pb = h1u + (size_t)(n*128 + icb + kb*8)*16384
                        + (((unsigned)ih < 128u) ? ih : 0)*128;
    uint m2[4];
    #pragma unroll
    for (int dx = 0; dx < 4; ++dx) m2[dx] = mskd[dx] & mih;

    uint raw[32];
    #pragma unroll
    for (int c = 0; c < 8; ++c)
      #pragma unroll
      for (int dx = 0; dx < 4; ++dx)
        raw[c*4 + dx] = pb[c*16384 + off[dx]] & m2[dx];

    uint hi16[16], lo16[16];
    #pragma unroll
    for (int q = 0; q < 16; ++q) {
      uint a = raw[2*q], b = raw[2*q+1];
      hi16[q] = (a & 0xffffu) | (b << 16);
      lo16[q] = (a >> 16) | (b & 0xffff0000u);
    }
    __syncthreads();
    #pragma unroll
    for (int i = 0; i < 4; ++i) {
      *(uint4*)&Ah[aw + i*8] = *(uint4*)&hi16[4*i];
      *(uint4*)&Al[aw + i*8] = *(uint4*)&lo16[4*i];
    }
    // B: 128 oc rows x 64 k, 4 uint4 per thread per buffer
    #pragma unroll
    for (int i = 0; i < 4; ++i) {
      int id = i*256 + t, oc = id >> 3, ch = id & 7;
      size_t bo = (size_t)(nt*128 + oc)*2048 + k0 + ch*8;
      *(uint4*)&Bhs[oc*72 + ch*8] = *(const uint4*)(Bh + bo);
      *(uint4*)&Bls[oc*72 + ch*8] = *(const uint4*)(Bl + bo);
    }
    __syncthreads();

    #pragma unroll
    for (int ks = 0; ks < 2; ++ks) {
      bh8 afh[4], afl[4];
      #pragma unroll
      for (int fm = 0; fm < 4; ++fm) {
        const int r = (wm*64 + fm*16 + lr)*72 + ks*32 + lg*8;
        afh[fm] = *(const bh8*)&Ah[r];
        afl[fm] = *(const bh8*)&Al[r];
      }
      #pragma unroll
      for (int fn = 0; fn < 4; ++fn) {
        const int r = (wn*64 + fn*16 + lr)*72 + ks*32 + lg*8;
        bh8 bfh = *(const bh8*)&Bhs[r];
        bh8 bfl = *(const bh8*)&Bls[r];
        #pragma unroll
        for (int fm = 0; fm < 4; ++fm) {
          acc[fm][fn] = __builtin_amdgcn_mfma_f32_16x16x32_bf16(afh[fm], bfh, acc[fm][fn], 0,0,0);
          acc[fm][fn] = __builtin_amdgcn_mfma_f32_16x16x32_bf16(afl[fm], bfh, acc[fm][fn], 0,0,0);
          acc[fm][fn] = __builtin_amdgcn_mfma_f32_16x16x32_bf16(afh[fm], bfl, acc[fm][fn], 0,0,0);
        }
      }
    }
  }

  #pragma unroll
  for (int fm = 0; fm < 4; ++fm) {
    const int pq = mt*128 + wm*64 + fm*16 + lg*4;
    const int nn = pq >> 12, hwq = pq & 4095;
    #pragma unroll
    for (int fn = 0; fn < 4; ++fn) {
      const int oc = nt*128 + wn*64 + fn*16 + lr;
      const float bv = bias[oc];
      float v0 = fmaxf(acc[fm][fn][0] + bv, 0.f);
      float v1 = fmaxf(acc[fm][fn][1] + bv, 0.f);
      float v2 = fmaxf(acc[fm][fn][2] + bv, 0.f);
      float v3 = fmaxf(acc[fm][fn][3] + bv, 0.f);
      *(float4*)(out + (((size_t)(nn*256 + oc)) << 12) + hwq) = make_float4(v0,v1,v2,v3);
    }
  }
}

// ===========================================================================
// FUSED prevq (fp32 GEMM) + VQ argmin + quantize/loss/hist. 64 px/block.
// ===========================================================================
__global__ __launch_bounds__(256, 3) void prevq_vq(const float* __restrict__ h2,
                                                   const float* __restrict__ btp,
                                                   const float* __restrict__ pvb,
                                                   const float* __restrict__ emb,
                                                   const float* __restrict__ Et,
                                                   const float* __restrict__ enrm,
                                                   uint* __restrict__ qz32,
                                                   int* __restrict__ hist,
                                                   float* __restrict__ loss_sum) {
  __shared__ __align__(16) float SM[10944 + 16];
  float* Zs   = SM;                        // [64 d][68]  = 4352 f (persists)
  float* As   = SM + 4352;                 // phase1 1024 f
  float* Bs   = SM + 4352 + 1024;          // phase1 1024 f
  float* Es   = SM + 4352;                 // phase2 32*132 = 4224 f (aliases As/Bs)
  float* nrmS = SM + 4352 + 4224;          // 128 f
  float* redv = SM + 4352 + 4224 + 128;    // 1088 f
  int*   redi = (int*)(redv + 1088);       // 1088
  int*   sIdx = (int*)(redv + 2176);       // 64

  const int t = threadIdx.x;
  const int base = (int)blockIdx.x * 64;
  const int n = base >> 12, hwb = base & 4095;
  const int ti = t & 15, tj = t >> 4;

  // ---- Phase 1: prevq GEMM (BM=64, BN=64, K=256) ----
  {
    const int pl = t & 63, kb = t >> 6;
    const int hw = hwb + pl;
    float acc[4][4];
    #pragma unroll
    for (int i = 0; i < 4; ++i)
      #pragma unroll
      for (int j = 0; j < 4; ++j) acc[i][j] = 0.f;

    for (int k0 = 0; k0 < 256; k0 += 16) {
      #pragma unroll
      for (int jj = 0; jj < 4; ++jj) {
        int kr = jj*4 + kb;
        As[kr*64 + pl] = h2[((size_t)(n*256 + k0 + kr) << 12) + hw];
      }
      {
        int kr = t >> 4, c4 = t & 15;
        ((float4*)Bs)[kr*16 + c4] = *((const float4*)(btp + (size_t)(k0 + kr)*64) + c4);
      }
      __syncthreads();
      #pragma unroll
      for (int kk = 0; kk < 16; ++kk) {
        float a[4], b[4];
        *(float4*)&a[0] = *(const float4*)&As[kk*64 + ti*4];
        *(float4*)&b[0] = *(const float4*)&Bs[kk*64 + tj*4];
        #pragma unroll
        for (int i = 0; i < 4; ++i)
          #pragma unroll
          for (int j = 0; j < 4; ++j)
            acc[i][j] += a[i]*b[j];
      }
      __syncthreads();
    }
    #pragma unroll
    for (int j = 0; j < 4; ++j) {
      float bv = pvb[tj*4 + j];
      #pragma unroll
      for (int i = 0; i < 4; ++i)
        Zs[(tj*4 + j)*68 + ti*4 + i] = acc[i][j] + bv;
    }
  }

  // ---- Phase 2: argmin over 512 codes ----
  float bv[4]; int bi[4];
  #pragma unroll
  for (int i = 0; i < 4; ++i) { bv[i] = 3.402823466e38f; bi[i] = 0; }

  for (int c = 0; c < 4; ++c) {
    float acc[4][8];
    #pragma unroll
    for (int i = 0; i < 4; ++i)
      #pragma unroll
      for (int j = 0; j < 8; ++j) acc[i][j] = 0.f;

    for (int hh = 0; hh < 2; ++hh) {
      __syncthreads();
      #pragma unroll
      for (int i = 0; i < 4; ++i) {
        int fid = i*256 + t, row = fid >> 5, c4 = fid & 31;
        *(float4*)&Es[row*132 + c4*4] =
            *(const float4*)(Et + (size_t)(hh*32 + row)*512 + c*128 + c4*4);
      }
      if (hh == 0 && t < 128) nrmS[t] = enrm[c*128 + t];
      __syncthreads();
      #pragma unroll 4
      for (int kk = 0; kk < 32; ++kk) {
        float4 a0 = *(const float4*)&Zs[(hh*32 + kk)*68 + ti*4];
        float4 b0 = *(const float4*)&Es[kk*132 + tj*8];
        float4 b1 = *(const float4*)&Es[kk*132 + tj*8 + 4];
        float a[4] = {a0.x, a0.y, a0.z, a0.w};
        float b[8] = {b0.x,b0.y,b0.z,b0.w, b1.x,b1.y,b1.z,b1.w};
        #pragma unroll
        for (int i = 0; i < 4; ++i)
          #pragma unroll
          for (int j = 0; j < 8; ++j)
            acc[i][j] += a[i]*b[j];
      }
    }
    #pragma unroll
    for (int j = 0; j < 8; ++j) {
      int code = c*128 + tj*8 + j;
      float nv = nrmS[tj*8 + j];
      #pragma unroll
      for (int i = 0; i < 4; ++i) {
        float d = nv - 2.f*acc[i][j];
        if (d < bv[i]) { bv[i] = d; bi[i] = code; }
      }
    }
  }

  __syncthreads();
  #pragma unroll
  for (int i = 0; i < 4; ++i) {
    redv[(ti*4 + i)*17 + tj] = bv[i];
    redi[(ti*4 + i)*17 + tj] = bi[i];
  }
  __syncthreads();
  if (t < 64) {
    float best = 3.402823466e38f; int bid = 0x7fffffff;
    #pragma unroll
    for (int j = 0; j < 16; ++j) {
      float v = redv[t*17 + j]; int ix = redi[t*17 + j];
      if (v < best || (v == best && ix < bid)) { best = v; bid = ix; }
    }
    sIdx[t] = bid;
  }
  __syncthreads();

  // ---- Phase 3: quantize (packed pairs) + loss + hist ----
  const int px = t & 63, grp = t >> 6;
  const int ix = sIdx[px];
  const float* er = emb + (size_t)ix * 64 + grp*16;
  uint* qb = qz32 + ((size_t)(n*32 + grp*8))*4096 + hwb + px;
  float ls = 0.f;
  #pragma unroll
  for (int dp = 0; dp < 8; ++dp) {
    float e0 = er[2*dp], e1 = er[2*dp + 1];
    float z0 = Zs[(grp*16 + 2*dp)*68 + px];
    float z1 = Zs[(grp*16 + 2*dp + 1)*68 + px];
    float d0 = e0 - z0, d1 = e1 - z1;
    ls += d0*d0 + d1*d1;
    qb[(size_t)dp * 4096] = (uint)f2bf(e0) | ((uint)f2bf(e1) << 16);
  }
  if (t < 64) atomicAdd(&hist[ix], 1);
  #pragma unroll
  for (int o = 32; o; o >>= 1) ls += __shfl_down(ls, o, 64);
  if ((t & 63) == 0) atomicAdd(loss_sum, ls);
}

__global__ void finalize_kernel(const int* __restrict__ hist,
                                const float* __restrict__ loss_sum,
                                float* __restrict__ out_loss,
                                float* __restrict__ out_perp) {
  __shared__ float red[512];
  int t = threadIdx.x;
  float pr = (float)hist[t] * (1.f/32768.f);
  red[t] = pr * logf(pr + 1e-10f);
  __syncthreads();
  for (int s = 256; s; s >>= 1) {
    if (t < s) red[t] += red[t + s];
    __syncthreads();
  }
  if (t == 0) {
    out_loss[0] = 1.25f * loss_sum[0] * (1.f/2097152.f);
    out_perp[0] = expf(-red[0]);
  }
}

// ===========================================================================
// DECODER postvq/deconv1: 128x128 tile, BK=64, bf16 MFMA (conv2 shape).
// A: channel-pair-packed coalesced loads (verified r13 paths).
// Epilogue: oc-pair packed via shfl_xor (verified r11/r13 pattern).
// ===========================================================================
enum { M_POSTVQ, M_DECONV1, M_DECONV2 };

template<int MODE>
__global__ __launch_bounds__(256, 4) void dec_mfma128(const uint* __restrict__ srcu,
                                                      const u16* __restrict__ Bt,
                                                      const float* __restrict__ bias,
                                                      uint* __restrict__ out32) {
  constexpr int K = (MODE == M_POSTVQ) ? 576 : 1024;
  __shared__ __align__(16) u16 As[128*72 + 32];
  __shared__ __align__(16) u16 Bs[128*72 + 32];

  const int t = threadIdx.x;
  int bid = xcd_swz((int)blockIdx.x, (int)gridDim.x);
  int par = 0, nt = 0, mt;
  if constexpr (MODE == M_DECONV1) { par = bid & 3; mt = bid >> 2; }
  else                             { nt = bid & 1;  mt = bid >> 1; }
  const u16* Brow = Bt + (size_t)((MODE == M_DECONV1) ? par*128 : nt*128) * K;

  const int pl = t & 127, kb = t >> 7;
  const int p = mt*128 + pl;
  const int n = p >> 12, h = (p >> 6) & 63, w = p & 63;
  const int lane = t & 63, wv = t >> 6;
  const int lr = lane & 15, lg = lane >> 4;
  const int wm = wv & 1, wn = wv >> 1;

  f32x4 acc[4][4];
  #pragma unroll
  for (int fm = 0; fm < 4; ++fm)
    #pragma unroll
    for (int fn = 0; fn < 4; ++fn)
      #pragma unroll
      for (int q = 0; q < 4; ++q) acc[fm][fn][q] = 0.f;

  const int aw = pl*72 + kb*32;

  for (int k0 = 0; k0 < K; k0 += 64) {
    // ---- A: 16 coalesced packed-uint loads (32 k's per kb half) ----
    const uint* up; bool ok;
    if constexpr (MODE == M_POSTVQ) {
      int r = k0 >> 6, kh = r / 3, kw = r - 3*kh;
      int ih = h - 1 + kh, iw = w - 1 + kw;
      ok = ((unsigned)ih < 64u) && ((unsigned)iw < 64u);
      up = srcu + ((size_t)(n*32 + kb*16)) * 4096
                + (ok ? ((ih << 6) + iw) : 0);
    } else {
      int j = k0 >> 8, icb = k0 & 255;
      int j1 = j >> 1, j0 = j & 1;
      int py = par >> 1, px = par & 1;
      int ih = h + py - 1 + j1, iw = w + px - 1 + j0;
      ok = ((unsigned)ih < 64u) && ((unsigned)iw < 64u);
      up = srcu + ((size_t)(n*128 + (icb >> 1) + kb*16)) * 4096
                + (ok ? ((ih << 6) + iw) : 0);
    }
    uint raw[16];
    #pragma unroll
    for (int i = 0; i < 16; ++i)
      raw[i] = ok ? up[(size_t)i * 4096] : 0u;

    __syncthreads();
    #pragma unroll
    for (int i = 0; i < 4; ++i)
      *(uint4*)&As[aw + i*8] =
          make_uint4(raw[4*i], raw[4*i+1], raw[4*i+2], raw[4*i+3]);

    // ---- B: 128 oc rows x 64 k, 4 uint4 per thread ----
    #pragma unroll
    for (int i = 0; i < 4; ++i) {
      int id = i*256 + t, oc = id >> 3, ch = id & 7;
      *(uint4*)&Bs[oc*72 + ch*8] = *(const uint4*)(Brow + (size_t)oc*K + k0 + ch*8);
    }
    __syncthreads();

    #pragma unroll
    for (int ks = 0; ks < 2; ++ks) {
      bh8 af[4];
      #pragma unroll
      for (int fm = 0; fm < 4; ++fm)
        af[fm] = *(const bh8*)&As[(wm*64 + fm*16 + lr)*72 + ks*32 + lg*8];
      #pragma unroll
      for (int fn = 0; fn < 4; ++fn) {
        bh8 bf = *(const bh8*)&Bs[(wn*64 + fn*16 + lr)*72 + ks*32 + lg*8];
        #pragma unroll
        for (int fm = 0; fm < 4; ++fm)
          acc[fm][fn] = __builtin_amdgcn_mfma_f32_16x16x32_bf16(af[fm], bf, acc[fm][fn], 0, 0, 0);
      }
    }
  }

  // ---- epilogue: bias (+ReLU), oc-pair pack, uint2 stores ----
  const bool evn = !(lr & 1);
  #pragma unroll
  for (int fm = 0; fm < 4; ++fm) {
    const int pq = mt*128 + wm*64 + fm*16 + lg*4;
    const int nn = pq >> 12, hwq = pq & 4095;
    #pragma unroll
    for (int fn = 0; fn < 4; ++fn) {
      const int oc = nt*128 + wn*64 + fn*16 + lr;
      const float bvv = bias[oc];
      float v[4];
      #pragma unroll
      for (int q = 0; q < 4; ++q) {
        v[q] = acc[fm][fn][q] + bvv;
        if constexpr (MODE == M_DECONV1) v[q] = fmaxf(v[q], 0.f);
      }
      float pv[4];
      #pragma unroll
      for (int q = 0; q < 4; ++q) pv[q] = __shfl_xor(v[q], 1, 64);
      uint pk[4];
      #pragma unroll
      for (int q = 0; q < 4; ++q) {
        u16 a = f2bf(evn ? v[q] : pv[q]);
        u16 b = f2bf(evn ? pv[q] : v[q]);
        pk[q] = (uint)a | ((uint)b << 16);
      }
      size_t pbase;
      if constexpr (MODE == M_POSTVQ)
        pbase = ((size_t)(nn*128 + (oc >> 1))) * 4096 + hwq;
      else
        pbase = ((size_t)((nn*4 + par)*64 + (oc >> 1))) * 4096 + hwq;
      if (evn) *(uint2*)(out32 + pbase)     = make_uint2(pk[0], pk[1]);
      else     *(uint2*)(out32 + pbase + 2) = make_uint2(pk[2], pk[3]);
    }
  }
}

// ===========================================================================
// DECODER deconv2 (BN=16, verified r13 path, unchanged)
// ===========================================================================
__global__ __launch_bounds__(256, 4) void deconv2_mfma(const uint* __restrict__ srcu,
                                                       const u16* __restrict__ Bt,
                                                       const float* __restrict__ bias,
                                                       float* __restrict__ outf) {
  constexpr int K = 512, BN = 16;
  __shared__ __align__(16) u16 As[128 * 72];
  __shared__ __align__(16) u16 Bs[BN * 72];

  const int t = threadIdx.x;
  int bid = xcd_swz((int)blockIdx.x, (int)gridDim.x);
  int par = bid & 3; bid >>= 2;
  const int mt = bid;
  const u16* Brow = Bt + (size_t)par * BN * K;

  const int pl = t & 127, kb = t >> 7;
  const int p = mt * 128 + pl;
  const int n = p >> 14, h = (p >> 7) & 127, w = p & 127;

  const int lane = t & 63, wv = t >> 6;
  const int lr = lane & 15, lg = lane >> 4;

  f32x4 acc[2];
  #pragma unroll
  for (int fm = 0; fm < 2; ++fm)
    #pragma unroll
    for (int q = 0; q < 4; ++q) acc[fm][q] = 0.f;

  for (int k0 = 0; k0 < K; k0 += 64) {
    int tap = k0 >> 7, icb = k0 & 127;
    int j1 = tap >> 1, j0 = tap & 1;
    int qy = par >> 1, qx = par & 1;
    int ih = h - 1 + qy + j1, iw = w - 1 + qx + j0;
    bool ok = ((unsigned)ih < 128u) && ((unsigned)iw < 128u);
    int ipar = ((ih & 1) << 1) | (iw & 1);
    const uint* up = srcu + ((size_t)((n*4 + ipar)*64 + (icb >> 1) + kb*16)) * 4096
                          + (ok ? (((ih >> 1) << 6) + (iw >> 1)) : 0);
    uint raw[16];
    #pragma unroll
    for (int i = 0; i < 16; ++i)
      raw[i] = ok ? up[(size_t)i * 4096] : 0u;

    __syncthreads();
    #pragma unroll
    for (int i = 0; i < 4; ++i)
      *(uint4*)&As[pl*72 + kb*32 + i*8] =
          make_uint4(raw[4*i], raw[4*i+1], raw[4*i+2], raw[4*i+3]);
    {
      int id = t;
      if (id < BN*8) {
        int oc = id >> 3, ch = id & 7;
        *(uint4*)&Bs[oc*72 + ch*8] = *(const uint4*)(Brow + (size_t)oc*K + k0 + ch*8);
      }
    }
    __syncthreads();

    #pragma unroll
    for (int ks = 0; ks < 2; ++ks) {
      bh8 af[2];
      #pragma unroll
      for (int fm = 0; fm < 2; ++fm)
        af[fm] = *(const bh8*)&As[(wv*32 + fm*16 + lr)*72 + ks*32 + lg*8];
      bh8 bf = *(const bh8*)&Bs[lr*72 + ks*32 + lg*8];
      #pragma unroll
      for (int fm = 0; fm < 2; ++fm)
        acc[fm] = __builtin_amdgcn_mfma_f32_16x16x32_bf16(af[fm], bf, acc[fm], 0, 0, 0);
    }
  }

  #pragma unroll
  for (int fm = 0; fm < 2; ++fm) {
    const int pq = mt*128 + wv*32 + fm*16 + lg*4;
    const int oc = lr;
    if (oc < 3) {
      const float bvv = bias[oc];
      const int nn = pq >> 14;
      const int hq = (pq >> 7) & 127, wq = pq & 127;
      const int qy = par >> 1, qx = par & 1;
      const int oh = 2*hq + qy;
      float* ob = outf + (((size_t)(nn*3 + oc)) << 16) + (oh << 8) + qx;
      ob[2*wq]     = acc[fm][0] + bvv;
      ob[2*wq + 2] = acc[fm][1] + bvv;
      ob[2*wq + 4] = acc[fm][2] + bvv;
      ob[2*wq + 6] = acc[fm][3] + bvv;
    }
  }
}

// ===========================================================================
// Weight preps
// ===========================================================================
__global__ void prep_enc(const float* __restrict__ ew1, const float* __restrict__ ew2,
                         const float* __restrict__ pvw, const float* __restrict__ emb,
                         float* bt1, u16* bt2h, u16* bt2l, float* btp,
                         float* Et, float* enrm) {
  int i = blockIdx.x * 256 + threadIdx.x;
  if (i < 6144) {
    int k = i >> 7, oc = i & 127;
    bt1[i] = ew1[oc*48 + k];
  } else if ((i -= 6144) < 524288) {            // bt2h/l [oc][k'=dy*512+ic*4+dx]
    int oc = i >> 11, k = i & 2047;
    int dy = k >> 9, ic = (k >> 2) & 127, dx = k & 3;
    float v = ew2[oc*2048 + ic*16 + dy*4 + dx];
    u16 hi = f2bf(v);
    bt2h[i] = hi;
    bt2l[i] = f2bf(v - bf2f(hi));
  } else if ((i -= 524288) < 16384) {           // btp [k][64]
    int k = i >> 6, oc = i & 63;
    btp[i] = pvw[oc*256 + k];
  } else if ((i -= 16384) < 32768) {            // Et [d][code] fp32
    int d = i >> 9, code = i & 511;
    Et[i] = emb[code*64 + d];
  } else if ((i -= 32768) < 512) {              // ||e||^2 fp32
    float s = 0.f;
    const float* er = emb + (size_t)i * 64;
    #pragma unroll
    for (int d = 0; d < 64; ++d) s += er[d]*er[d];
    enrm[i] = s;
  }
}

__global__ void prep_dec(const float* __restrict__ qvw, const float* __restrict__ dw1,
                         const float* __restrict__ dw2,
                         u16* btq, u16* btd, u16* btd2) {
  int i = blockIdx.x * 256 + threadIdx.x;
  if (i < 147456) {                             // btq [oc][k=r*64+ic]
    int oc = i / 576, rem = i - oc*576, r = rem >> 6, ic = rem & 63;
    btq[i] = f2bf(qvw[oc*576 + ic*9 + r]);
  } else if ((i -= 147456) < 524288) {          // btd [par][oc][k=j*256+ic]
    int pr = i >> 17, oc = (i >> 10) & 127, j = (i >> 8) & 3, ic = i & 255;
    int py = pr >> 1, px = pr & 1, j1 = j >> 1, j0 = j & 1;
    btd[i] = f2bf(dw1[oc*4096 + ic*16 + (py + 2*j1)*4 + (px + 2*j0)]);
  } else if ((i -= 524288) < 32768) {           // btd2 [q][oc16][k=tap*128+ic]
    int q = i >> 13, oc = (i >> 9) & 15, tap = (i >> 7) & 3, ic = i & 127;
    int qy = q >> 1, qx = q & 1, j1 = tap >> 1, j0 = tap & 1;
    btd2[i] = (oc < 3) ? f2bf(dw2[oc*2048 + ic*16 + (qy + 2*j1)*4 + (qx + 2*j0)]) : (u16)0;
  }
}

// ===========================================================================
extern "C" void kernel_launch(void* const* d_in, const int* in_sizes, int n_in,
                              void* d_out, int out_size, void* d_ws, size_t ws_size,
                              hipStream_t stream) {
  (void)in_sizes; (void)n_in; (void)ws_size;
  const float* x   = (const float*)d_in[0];
  const float* ew1 = (const float*)d_in[1];
  const float* eb1 = (const float*)d_in[2];
  const float* ew2 = (const float*)d_in[3];
  const float* eb2 = (const float*)d_in[4];
  const float* pvw = (const float*)d_in[5];
  const float* pvb = (const float*)d_in[6];
  const float* emb = (const float*)d_in[7];
  const float* qvw = (const float*)d_in[8];
  const float* qvb = (const float*)d_in[9];
  const float* dw1 = (const float*)d_in[10];
  const float* db1 = (const float*)d_in[11];
  const float* dw2 = (const float*)d_in[12];
  const float* db2 = (const float*)d_in[13];
  float* out = (float*)d_out;

  char* ws = (char*)d_ws;
  uint*  h1u  = (uint*) (ws);                    // packed hi/lo parity planes, 67108864 B
  float* h2   = (float*)(ws + 67108864);         // [8,256,64,64] f32, 33554432 B
  uint*  qz32 = (uint*) (ws + 109051904);        // [8][32 c2][4096] packed, 4194304 B
  int*   hist = (int*)  (ws + 113246208);        // 2048 B
  float* lsum = (float*)(ws + 113248256);        // 64 B
  float* bt1  = (float*)(ws + 113248320);        // 24576 B
  float* btp  = (float*)(ws + 113272896);        // 65536 B
  u16*   bt2h = (u16*)  (ws + 113338432);        // 1048576 B
  u16*   bt2l = (u16*)  (ws + 114387008);        // 1048576 B
  u16*   btq  = (u16*)  (ws + 115435584);        // 294912 B
  u16*   btd  = (u16*)  (ws + 115730496);        // 1048576 B
  u16*   btd2 = (u16*)  (ws + 116779072);        // 65536 B
  float* Et   = (float*)(ws + 116844608);        // 131072 B
  float* enrm = (float*)(ws + 116975680);        // 2048 B
  uint* g32  = (uint*)(ws + 67108864);  // [8][128 c2][4096] packed, overlays h2 (dead)
  uint* g232 = (uint*)ws;               // [8][4 par][64 c2][4096] packed, overlays h1u

  hipMemsetAsync(hist, 0, 2048 + 64, stream);
  prep_enc<<<2266, 256, 0, stream>>>(ew1, ew2, pvw, emb, bt1, bt2h, bt2l, btp, Et, enrm);
  prep_dec<<<2752, 256, 0, stream>>>(qvw, dw1, dw2, btq, btd, btd2);

  conv1_f32<<<4096, 256, 0, stream>>>(x, bt1, eb1, h1u);
  conv2_mfma3<<<512, 256, 0, stream>>>(h1u, bt2h, bt2l, eb2, h2);

  prevq_vq<<<512, 256, 0, stream>>>(h2, btp, pvb, emb, Et, enrm, qz32, hist, lsum);
  finalize_kernel<<<1, 512, 0, stream>>>(hist, lsum, out, out + (out_size - 1));

  dec_mfma128<M_POSTVQ> <<<512,  256, 0, stream>>>(qz32, btq, qvb, g32);
  dec_mfma128<M_DECONV1><<<1024, 256, 0, stream>>>(g32, btd, db1, g232);
  deconv2_mfma<<<4096, 256, 0, stream>>>(g232, btd2, db2, out + 1);
}

// Round 15
// 390.071 us; speedup vs baseline: 1.0243x; 1.0243x over previous
//
#include <hip/hip_runtime.h>
#include <math.h>

typedef unsigned short u16;
typedef unsigned int uint;
typedef __attribute__((ext_vector_type(8))) short bh8;   // 8 bf16 in 4 VGPRs
typedef __attribute__((ext_vector_type(4))) float f32x4;

#define DEV __device__ __forceinline__

DEV u16 f2bf(float x) {                       // fp32 -> bf16 RNE
  uint u = __builtin_bit_cast(uint, x);
  return (u16)((u + 0x7FFFu + ((u >> 16) & 1u)) >> 16);
}
DEV float bf2f(u16 h) { return __builtin_bit_cast(float, (uint)h << 16); }

// Bijective XCD-aware swizzle: 8 XCDs, contiguous chunk per XCD.
DEV int xcd_swz(int bid, int nb) {
  int c = nb >> 3;
  return (bid & 7) * c + (bid >> 3);
}

// ===========================================================================
// ENCODER stage 1: conv1 fp32 VALU implicit-GEMM (exact numerics).
// BM=64 x BN=64 tile, acc[4][4] (16 VGPR) -> no scratch spills.
// Emits h1 as packed-uint (hi|lo bf16) parity-split NCHW planes:
//   h1u[(n*128+oc)*16384 + ih*128 + (iw&1)*64 + (iw>>1)]
// ===========================================================================
__global__ __launch_bounds__(256, 4) void conv1_f32(const float* __restrict__ src,
                                                    const float* __restrict__ Bt,
                                                    const float* __restrict__ bias,
                                                    uint* __restrict__ outu) {
  __shared__ __align__(16) float As[16*64];
  __shared__ __align__(16) float Bs[16*64];

  const int t = threadIdx.x;
  const int bid = (int)blockIdx.x;
  const int nt = bid & 1, m = bid >> 1;      // m in [0,2048): (n, h, whalf)
  const int pl = t & 63, kb = t >> 6;        // kb 0..3
  const int p = m*64 + pl;
  const int n = p >> 14, h = (p >> 7) & 127, w = p & 127;
  const int ti = t & 15, tj = t >> 4;

  float acc[4][4];
  #pragma unroll
  for (int i = 0; i < 4; ++i)
    #pragma unroll
    for (int j = 0; j < 4; ++j) acc[i][j] = 0.f;

  for (int k0 = 0; k0 < 48; k0 += 16) {
    #pragma unroll
    for (int jj = 0; jj < 4; ++jj) {
      int kr = jj*4 + kb, k = k0 + kr;
      int ic = k >> 4, r = k & 15;
      int ih = 2*h - 1 + (r >> 2), iw = 2*w - 1 + (r & 3);
      As[kr*64 + pl] = ((unsigned)ih < 256u && (unsigned)iw < 256u)
        ? src[((n*3 + ic) << 16) + (ih << 8) + iw] : 0.f;
    }
    {
      int kr = t >> 4, c4 = t & 15;          // 16 rows x 16 float4
      ((float4*)Bs)[kr*16 + c4] =
          *((const float4*)(Bt + (size_t)(k0 + kr)*128 + nt*64) + c4);
    }
    __syncthreads();
    #pragma unroll
    for (int kk = 0; kk < 16; ++kk) {
      float a[4], b[4];
      *(float4*)&a[0] = *(const float4*)&As[kk*64 + ti*4];
      *(float4*)&b[0] = *(const float4*)&Bs[kk*64 + tj*4];
      #pragma unroll
      for (int i = 0; i < 4; ++i)
        #pragma unroll
        for (int j = 0; j < 4; ++j)
          acc[i][j] += a[i]*b[j];
    }
    __syncthreads();
  }

  // packed hi/lo epilogue (pixels w = woff + ti*4 + q)
  const int nn = m >> 8, hh = (m >> 1) & 127;
  const int woff2 = (m & 1) * 32;            // woff/2 in uints
  #pragma unroll
  for (int j = 0; j < 4; ++j) {
    const int oc = nt*64 + tj*4 + j;
    uint pk[4];
    #pragma unroll
    for (int q = 0; q < 4; ++q) {
      float v = fmaxf(acc[q][j] + bias[oc], 0.f);
      u16 hi = f2bf(v);
      u16 lo = f2bf(v - bf2f(hi));
      pk[q] = (uint)hi | ((uint)lo << 16);
    }
    uint* bp = outu + (size_t)(nn*128 + oc)*16384 + hh*128;
    *(uint2*)(bp + woff2 + ti*2)      = make_uint2(pk[0], pk[2]);
    *(uint2*)(bp + 64 + woff2 + ti*2) = make_uint2(pk[1], pk[3]);
  }
}

// ===========================================================================
// ENCODER stage 2: conv2 bf16x3 split MFMA. BM=128, BN=128, BK=64, grid 512.
// ===========================================================================
__global__ __launch_bounds__(256, 2) void conv2_mfma3(const uint* __restrict__ h1u,
                                                      const u16* __restrict__ Bh,
                                                      const u16* __restrict__ Bl,
                                                      const float* __restrict__ bias,
                                                      float* __restrict__ out) {
  __shared__ __align__(16) u16 Ah[128*72 + 32];
  __shared__ __align__(16) u16 Al[128*72 + 32];
  __shared__ __align__(16) u16 Bhs[128*72 + 32];
  __shared__ __align__(16) u16 Bls[128*72 + 32];

  const int t = threadIdx.x;
  const int bid = xcd_swz((int)blockIdx.x, (int)gridDim.x);
  const int nt = bid & 1, mt = bid >> 1;
  const int pl = t & 127, kb = t >> 7;
  const int p = mt*128 + pl;
  const int n = p >> 12, h = (p >> 6) & 63, w = p & 63;
  const int lane = t & 63, wv = t >> 6;
  const int lr = lane & 15, lg = lane >> 4;
  const int wm = wv & 1, wn = wv >> 1;

  int off[4]; uint mskd[4];
  off[0] = 64 + w - 1; mskd[0] = (w >= 1)  ? ~0u : 0u;
  off[1] = w;          mskd[1] = ~0u;
  off[2] = 64 + w;     mskd[2] = ~0u;
  off[3] = w + 1;      mskd[3] = (w <= 62) ? ~0u : 0u;

  f32x4 acc[4][4];
  #pragma unroll
  for (int fm = 0; fm < 4; ++fm)
    #pragma unroll
    for (int fn = 0; fn < 4; ++fn)
      #pragma unroll
      for (int q = 0; q < 4; ++q) acc[fm][fn][q] = 0.f;

  const int aw = pl*72 + kb*32;

  for (int k0 = 0; k0 < 2048; k0 += 64) {
    const int dy = k0 >> 9, icb = (k0 >> 2) & 127;   // ic block of 16 (8 per kb)
    const int ih = 2*h - 1 + dy;
    const uint mih = ((unsigned)ih < 128u) ? ~0u : 0u;
    const uint* pb = h1u + (size_t)(n*128 + icb + kb*8)*16384
                        + (((unsigned)ih < 128u) ? ih : 0)*128;
    uint m2[4];
    #pragma unroll
    for (int dx = 0; dx < 4; ++dx) m2[dx] = mskd[dx] & mih;

    uint raw[32];
    #pragma unroll
    for (int c = 0; c < 8; ++c)
      #pragma unroll
      for (int dx = 0; dx < 4; ++dx)
        raw[c*4 + dx] = pb[c*16384 + off[dx]] & m2[dx];

    uint hi16[16], lo16[16];
    #pragma unroll
    for (int q = 0; q < 16; ++q) {
      uint a = raw[2*q], b = raw[2*q+1];
      hi16[q] = (a & 0xffffu) | (b << 16);
      lo16[q] = (a >> 16) | (b & 0xffff0000u);
    }
    __syncthreads();
    #pragma unroll
    for (int i = 0; i < 4; ++i) {
      *(uint4*)&Ah[aw + i*8] = *(uint4*)&hi16[4*i];
      *(uint4*)&Al[aw + i*8] = *(uint4*)&lo16[4*i];
    }
    // B: 128 oc rows x 64 k, 4 uint4 per thread per buffer
    #pragma unroll
    for (int i = 0; i < 4; ++i) {
      int id = i*256 + t, oc = id >> 3, ch = id & 7;
      size_t bo = (size_t)(nt*128 + oc)*2048 + k0 + ch*8;
      *(uint4*)&Bhs[oc*72 + ch*8] = *(const uint4*)(Bh + bo);
      *(uint4*)&Bls[oc*72 + ch*8] = *(const uint4*)(Bl + bo);
    }
    __syncthreads();

    #pragma unroll
    for (int ks = 0; ks < 2; ++ks) {
      bh8 afh[4], afl[4];
      #pragma unroll
      for (int fm = 0; fm < 4; ++fm) {
        const int r = (wm*64 + fm*16 + lr)*72 + ks*32 + lg*8;
        afh[fm] = *(const bh8*)&Ah[r];
        afl[fm] = *(const bh8*)&Al[r];
      }
      #pragma unroll
      for (int fn = 0; fn < 4; ++fn) {
        const int r = (wn*64 + fn*16 + lr)*72 + ks*32 + lg*8;
        bh8 bfh = *(const bh8*)&Bhs[r];
        bh8 bfl = *(const bh8*)&Bls[r];
        #pragma unroll
        for (int fm = 0; fm < 4; ++fm) {
          acc[fm][fn] = __builtin_amdgcn_mfma_f32_16x16x32_bf16(afh[fm], bfh, acc[fm][fn], 0,0,0);
          acc[fm][fn] = __builtin_amdgcn_mfma_f32_16x16x32_bf16(afl[fm], bfh, acc[fm][fn], 0,0,0);
          acc[fm][fn] = __builtin_amdgcn_mfma_f32_16x16x32_bf16(afh[fm], bfl, acc[fm][fn], 0,0,0);
        }
      }
    }
  }

  #pragma unroll
  for (int fm = 0; fm < 4; ++fm) {
    const int pq = mt*128 + wm*64 + fm*16 + lg*4;
    const int nn = pq >> 12, hwq = pq & 4095;
    #pragma unroll
    for (int fn = 0; fn < 4; ++fn) {
      const int oc = nt*128 + wn*64 + fn*16 + lr;
      const float bv = bias[oc];
      float v0 = fmaxf(acc[fm][fn][0] + bv, 0.f);
      float v1 = fmaxf(acc[fm][fn][1] + bv, 0.f);
      float v2 = fmaxf(acc[fm][fn][2] + bv, 0.f);
      float v3 = fmaxf(acc[fm][fn][3] + bv, 0.f);
      *(float4*)(out + (((size_t)(nn*256 + oc)) << 12) + hwq) = make_float4(v0,v1,v2,v3);
    }
  }
}

// ===========================================================================
// FUSED prevq (fp32 GEMM) + VQ argmin (bf16x3 MFMA) + quantize/loss/hist.
// 64 px/block. Argmin scores = Zh*Eh + Zl*Eh + Zh*El (error ~2^-17, ~100x
// below min top-2 gap). Phase1 (z) and phase3 (loss/quantize) exact fp32.
// ===========================================================================
__global__ __launch_bounds__(256, 2) void prevq_vq(const float* __restrict__ h2,
                                                   const float* __restrict__ btp,
                                                   const float* __restrict__ pvb,
                                                   const float* __restrict__ emb,
                                                   const u16* __restrict__ Ebh,
                                                   const u16* __restrict__ Ebl,
                                                   const float* __restrict__ enrm,
                                                   uint* __restrict__ qz32,
                                                   int* __restrict__ hist,
                                                   float* __restrict__ loss_sum) {
  __shared__ __align__(16) char SMEM[75776];
  float* Zs    = (float*)SMEM;                 // [64 d][68] fp32, 17408 B (persists)
  u16*   Zh    = (u16*)(SMEM + 17408);         // [64 px][72], 9216 B
  u16*   Zl    = (u16*)(SMEM + 26624);         // [64 px][72], 9216 B
  u16*   Eh    = (u16*)(SMEM + 35840);         // [128 code][72], 18432 B
  u16*   El    = (u16*)(SMEM + 54272);         // [128 code][72], 18432 B
  float* nrmS  = (float*)(SMEM + 72704);       // 128 f
  float* wredv = (float*)(SMEM + 73216);       // [4 wv][64 px]
  int*   wredi = (int*)(SMEM + 74240);         // [4 wv][64 px]
  int*   sIdx  = (int*)(SMEM + 75264);         // 64
  float* As    = (float*)(SMEM + 35840);       // phase1 alias, 4096 B
  float* Bs    = (float*)(SMEM + 35840 + 4096);// phase1 alias, 4096 B

  const int t = threadIdx.x;
  const int base = (int)blockIdx.x * 64;
  const int n = base >> 12, hwb = base & 4095;
  const int ti = t & 15, tj = t >> 4;

  // ---- Phase 1: prevq GEMM (BM=64, BN=64, K=256), exact fp32 ----
  {
    const int pl = t & 63, kb = t >> 6;
    const int hw = hwb + pl;
    float acc[4][4];
    #pragma unroll
    for (int i = 0; i < 4; ++i)
      #pragma unroll
      for (int j = 0; j < 4; ++j) acc[i][j] = 0.f;

    for (int k0 = 0; k0 < 256; k0 += 16) {
      #pragma unroll
      for (int jj = 0; jj < 4; ++jj) {
        int kr = jj*4 + kb;
        As[kr*64 + pl] = h2[((size_t)(n*256 + k0 + kr) << 12) + hw];
      }
      {
        int kr = t >> 4, c4 = t & 15;
        ((float4*)Bs)[kr*16 + c4] = *((const float4*)(btp + (size_t)(k0 + kr)*64) + c4);
      }
      __syncthreads();
      #pragma unroll
      for (int kk = 0; kk < 16; ++kk) {
        float a[4], b[4];
        *(float4*)&a[0] = *(const float4*)&As[kk*64 + ti*4];
        *(float4*)&b[0] = *(const float4*)&Bs[kk*64 + tj*4];
        #pragma unroll
        for (int i = 0; i < 4; ++i)
          #pragma unroll
          for (int j = 0; j < 4; ++j)
            acc[i][j] += a[i]*b[j];
      }
      __syncthreads();
    }
    // z -> Zs (fp32) and Zh/Zl (bf16 hi/lo, [px][d])
    #pragma unroll
    for (int j = 0; j < 4; ++j) {
      const int d = tj*4 + j;
      const float bvv = pvb[d];
      #pragma unroll
      for (int i = 0; i < 4; ++i) {
        const int px = ti*4 + i;
        float z = acc[i][j] + bvv;
        Zs[d*68 + px] = z;
        u16 h = f2bf(z);
        Zh[px*72 + d] = h;
        Zl[px*72 + d] = f2bf(z - bf2f(h));
      }
    }
  }

  // ---- Phase 2: argmin via bf16x3 MFMA over 4 chunks of 128 codes ----
  const int lane = t & 63, wv = t >> 6;
  const int lr = lane & 15, lg = lane >> 4;

  float bv2[4][4]; int bi2[4][4];          // [fm][q]: px = fm*16 + lg*4 + q
  #pragma unroll
  for (int fm = 0; fm < 4; ++fm)
    #pragma unroll
    for (int q = 0; q < 4; ++q) { bv2[fm][q] = 3.402823466e38f; bi2[fm][q] = 0; }

  for (int c = 0; c < 4; ++c) {
    __syncthreads();
    #pragma unroll
    for (int i = 0; i < 4; ++i) {
      int id = i*256 + t, row = id >> 3, ch = id & 7;
      *(uint4*)&Eh[row*72 + ch*8] = *(const uint4*)(Ebh + (size_t)(c*128 + row)*64 + ch*8);
      *(uint4*)&El[row*72 + ch*8] = *(const uint4*)(Ebl + (size_t)(c*128 + row)*64 + ch*8);
    }
    if (t < 128) nrmS[t] = enrm[c*128 + t];
    __syncthreads();

    f32x4 acc2[4][2];
    #pragma unroll
    for (int fm = 0; fm < 4; ++fm)
      #pragma unroll
      for (int fn = 0; fn < 2; ++fn)
        #pragma unroll
        for (int q = 0; q < 4; ++q) acc2[fm][fn][q] = 0.f;

    #pragma unroll
    for (int ks = 0; ks < 2; ++ks) {
      bh8 ah[4], al[4];
      #pragma unroll
      for (int fm = 0; fm < 4; ++fm) {
        const int r = (fm*16 + lr)*72 + ks*32 + lg*8;
        ah[fm] = *(const bh8*)&Zh[r];
        al[fm] = *(const bh8*)&Zl[r];
      }
      #pragma unroll
      for (int fn = 0; fn < 2; ++fn) {
        const int r = (wv*32 + fn*16 + lr)*72 + ks*32 + lg*8;
        bh8 bh_ = *(const bh8*)&Eh[r];
        bh8 bl_ = *(const bh8*)&El[r];
        #pragma unroll
        for (int fm = 0; fm < 4; ++fm) {
          acc2[fm][fn] = __builtin_amdgcn_mfma_f32_16x16x32_bf16(ah[fm], bh_, acc2[fm][fn], 0,0,0);
          acc2[fm][fn] = __builtin_amdgcn_mfma_f32_16x16x32_bf16(al[fm], bh_, acc2[fm][fn], 0,0,0);
          acc2[fm][fn] = __builtin_amdgcn_mfma_f32_16x16x32_bf16(ah[fm], bl_, acc2[fm][fn], 0,0,0);
        }
      }
    }
    // running argmin: dist = ||e||^2 - 2 z.e ; codes strictly increasing per slot
    #pragma unroll
    for (int fn = 0; fn < 2; ++fn) {
      const int code = c*128 + wv*32 + fn*16 + lr;
      const float nv = nrmS[wv*32 + fn*16 + lr];
      #pragma unroll
      for (int fm = 0; fm < 4; ++fm)
        #pragma unroll
        for (int q = 0; q < 4; ++q) {
          float d = nv - 2.f*acc2[fm][fn][q];
          if (d < bv2[fm][q]) { bv2[fm][q] = d; bi2[fm][q] = code; }
        }
    }
  }

  // per-wave reduce over lr lanes, then cross-wave via LDS
  #pragma unroll
  for (int fm = 0; fm < 4; ++fm)
    #pragma unroll
    for (int q = 0; q < 4; ++q) {
      float v = bv2[fm][q]; int ix = bi2[fm][q];
      #pragma unroll
      for (int m = 1; m < 16; m <<= 1) {
        float ov = __shfl_xor(v, m, 64);
        int   oi = __shfl_xor(ix, m, 64);
        if (ov < v || (ov == v && oi < ix)) { v = ov; ix = oi; }
      }
      if (lr == 0) {
        const int px = fm*16 + lg*4 + q;
        wredv[wv*64 + px] = v;
        wredi[wv*64 + px] = ix;
      }
    }
  __syncthreads();
  if (t < 64) {
    float best = 3.402823466e38f; int bid = 0x7fffffff;
    #pragma unroll
    for (int w2 = 0; w2 < 4; ++w2) {
      float v = wredv[w2*64 + t]; int ix = wredi[w2*64 + t];
      if (v < best || (v == best && ix < bid)) { best = v; bid = ix; }
    }
    sIdx[t] = bid;
  }
  __syncthreads();

  // ---- Phase 3: quantize (packed pairs) + loss + hist (exact fp32) ----
  const int px = t & 63, grp = t >> 6;
  const int ix = sIdx[px];
  const float* er = emb + (size_t)ix * 64 + grp*16;
  uint* qb = qz32 + ((size_t)(n*32 + grp*8))*4096 + hwb + px;
  float ls = 0.f;
  #pragma unroll
  for (int dp = 0; dp < 8; ++dp) {
    float e0 = er[2*dp], e1 = er[2*dp + 1];
    float z0 = Zs[(grp*16 + 2*dp)*68 + px];
    float z1 = Zs[(grp*16 + 2*dp + 1)*68 + px];
    float d0 = e0 - z0, d1 = e1 - z1;
    ls += d0*d0 + d1*d1;
    qb[(size_t)dp * 4096] = (uint)f2bf(e0) | ((uint)f2bf(e1) << 16);
  }
  if (t < 64) atomicAdd(&hist[ix], 1);
  #pragma unroll
  for (int o = 32; o; o >>= 1) ls += __shfl_down(ls, o, 64);
  if ((t & 63) == 0) atomicAdd(loss_sum, ls);
}

__global__ void finalize_kernel(const int* __restrict__ hist,
                                const float* __restrict__ loss_sum,
                                float* __restrict__ out_loss,
                                float* __restrict__ out_perp) {
  __shared__ float red[512];
  int t = threadIdx.x;
  float pr = (float)hist[t] * (1.f/32768.f);
  red[t] = pr * logf(pr + 1e-10f);
  __syncthreads();
  for (int s = 256; s; s >>= 1) {
    if (t < s) red[t] += red[t + s];
    __syncthreads();
  }
  if (t == 0) {
    out_loss[0] = 1.25f * loss_sum[0] * (1.f/2097152.f);
    out_perp[0] = expf(-red[0]);
  }
}

// ===========================================================================
// DECODER postvq/deconv1: 128x128 tile, BK=64, bf16 MFMA (r14, verified).
// ===========================================================================
enum { M_POSTVQ, M_DECONV1, M_DECONV2 };

template<int MODE>
__global__ __launch_bounds__(256, 4) void dec_mfma128(const uint* __restrict__ srcu,
                                                      const u16* __restrict__ Bt,
                                                      const float* __restrict__ bias,
                                                      uint* __restrict__ out32) {
  constexpr int K = (MODE == M_POSTVQ) ? 576 : 1024;
  __shared__ __align__(16) u16 As[128*72 + 32];
  __shared__ __align__(16) u16 Bs[128*72 + 32];

  const int t = threadIdx.x;
  int bid = xcd_swz((int)blockIdx.x, (int)gridDim.x);
  int par = 0, nt = 0, mt;
  if constexpr (MODE == M_DECONV1) { par = bid & 3; mt = bid >> 2; }
  else                             { nt = bid & 1;  mt = bid >> 1; }
  const u16* Brow = Bt + (size_t)((MODE == M_DECONV1) ? par*128 : nt*128) * K;

  const int pl = t & 127, kb = t >> 7;
  const int p = mt*128 + pl;
  const int n = p >> 12, h = (p >> 6) & 63, w = p & 63;
  const int lane = t & 63, wv = t >> 6;
  const int lr = lane & 15, lg = lane >> 4;
  const int wm = wv & 1, wn = wv >> 1;

  f32x4 acc[4][4];
  #pragma unroll
  for (int fm = 0; fm < 4; ++fm)
    #pragma unroll
    for (int fn = 0; fn < 4; ++fn)
      #pragma unroll
      for (int q = 0; q < 4; ++q) acc[fm][fn][q] = 0.f;

  const int aw = pl*72 + kb*32;

  for (int k0 = 0; k0 < K; k0 += 64) {
    const uint* up; bool ok;
    if constexpr (MODE == M_POSTVQ) {
      int r = k0 >> 6, kh = r / 3, kw = r - 3*kh;
      int ih = h - 1 + kh, iw = w - 1 + kw;
      ok = ((unsigned)ih < 64u) && ((unsigned)iw < 64u);
      up = srcu + ((size_t)(n*32 + kb*16)) * 4096
                + (ok ? ((ih << 6) + iw) : 0);
    } else {
      int j = k0 >> 8, icb = k0 & 255;
      int j1 = j >> 1, j0 = j & 1;
      int py = par >> 1, px = par & 1;
      int ih = h + py - 1 + j1, iw = w + px - 1 + j0;
      ok = ((unsigned)ih < 64u) && ((unsigned)iw < 64u);
      up = srcu + ((size_t)(n*128 + (icb >> 1) + kb*16)) * 4096
                + (ok ? ((ih << 6) + iw) : 0);
    }
    uint raw[16];
    #pragma unroll
    for (int i = 0; i < 16; ++i)
      raw[i] = ok ? up[(size_t)i * 4096] : 0u;

    __syncthreads();
    #pragma unroll
    for (int i = 0; i < 4; ++i)
      *(uint4*)&As[aw + i*8] =
          make_uint4(raw[4*i], raw[4*i+1], raw[4*i+2], raw[4*i+3]);

    #pragma unroll
    for (int i = 0; i < 4; ++i) {
      int id = i*256 + t, oc = id >> 3, ch = id & 7;
      *(uint4*)&Bs[oc*72 + ch*8] = *(const uint4*)(Brow + (size_t)oc*K + k0 + ch*8);
    }
    __syncthreads();

    #pragma unroll
    for (int ks = 0; ks < 2; ++ks) {
      bh8 af[4];
      #pragma unroll
      for (int fm = 0; fm < 4; ++fm)
        af[fm] = *(const bh8*)&As[(wm*64 + fm*16 + lr)*72 + ks*32 + lg*8];
      #pragma unroll
      for (int fn = 0; fn < 4; ++fn) {
        bh8 bf = *(const bh8*)&Bs[(wn*64 + fn*16 + lr)*72 + ks*32 + lg*8];
        #pragma unroll
        for (int fm = 0; fm < 4; ++fm)
          acc[fm][fn] = __builtin_amdgcn_mfma_f32_16x16x32_bf16(af[fm], bf, acc[fm][fn], 0, 0, 0);
      }
    }
  }

  const bool evn = !(lr & 1);
  #pragma unroll
  for (int fm = 0; fm < 4; ++fm) {
    const int pq = mt*128 + wm*64 + fm*16 + lg*4;
    const int nn = pq >> 12, hwq = pq & 4095;
    #pragma unroll
    for (int fn = 0; fn < 4; ++fn) {
      const int oc = nt*128 + wn*64 + fn*16 + lr;
      const float bvv = bias[oc];
      float v[4];
      #pragma unroll
      for (int q = 0; q < 4; ++q) {
        v[q] = acc[fm][fn][q] + bvv;
        if constexpr (MODE == M_DECONV1) v[q] = fmaxf(v[q], 0.f);
      }
      float pv[4];
      #pragma unroll
      for (int q = 0; q < 4; ++q) pv[q] = __shfl_xor(v[q], 1, 64);
      uint pk[4];
      #pragma unroll
      for (int q = 0; q < 4; ++q) {
        u16 a = f2bf(evn ? v[q] : pv[q]);
        u16 b = f2bf(evn ? pv[q] : v[q]);
        pk[q] = (uint)a | ((uint)b << 16);
      }
      size_t pbase;
      if constexpr (MODE == M_POSTVQ)
        pbase = ((size_t)(nn*128 + (oc >> 1))) * 4096 + hwq;
      else
        pbase = ((size_t)((nn*4 + par)*64 + (oc >> 1))) * 4096 + hwq;
      if (evn) *(uint2*)(out32 + pbase)     = make_uint2(pk[0], pk[1]);
      else     *(uint2*)(out32 + pbase + 2) = make_uint2(pk[2], pk[3]);
    }
  }
}

// ===========================================================================
// DECODER deconv2 (BN=16, verified r13/r14 path, unchanged)
// ===========================================================================
__global__ __launch_bounds__(256, 4) void deconv2_mfma(const uint* __restrict__ srcu,
                                                       const u16* __restrict__ Bt,
                                                       const float* __restrict__ bias,
                                                       float* __restrict__ outf) {
  constexpr int K = 512, BN = 16;
  __shared__ __align__(16) u16 As[128 * 72];
  __shared__ __align__(16) u16 Bs[BN * 72];

  const int t = threadIdx.x;
  int bid = xcd_swz((int)blockIdx.x, (int)gridDim.x);
  int par = bid & 3; bid >>= 2;
  const int mt = bid;
  const u16* Brow = Bt + (size_t)par * BN * K;

  const int pl = t & 127, kb = t >> 7;
  const int p = mt * 128 + pl;
  const int n = p >> 14, h = (p >> 7) & 127, w = p & 127;

  const int lane = t & 63, wv = t >> 6;
  const int lr = lane & 15, lg = lane >> 4;

  f32x4 acc[2];
  #pragma unroll
  for (int fm = 0; fm < 2; ++fm)
    #pragma unroll
    for (int q = 0; q < 4; ++q) acc[fm][q] = 0.f;

  for (int k0 = 0; k0 < K; k0 += 64) {
    int tap = k0 >> 7, icb = k0 & 127;
    int j1 = tap >> 1, j0 = tap & 1;
    int qy = par >> 1, qx = par & 1;
    int ih = h - 1 + qy + j1, iw = w - 1 + qx + j0;
    bool ok = ((unsigned)ih < 128u) && ((unsigned)iw < 128u);
    int ipar = ((ih & 1) << 1) | (iw & 1);
    const uint* up = srcu + ((size_t)((n*4 + ipar)*64 + (icb >> 1) + kb*16)) * 4096
                          + (ok ? (((ih >> 1) << 6) + (iw >> 1)) : 0);
    uint raw[16];
    #pragma unroll
    for (int i = 0; i < 16; ++i)
      raw[i] = ok ? up[(size_t)i * 4096] : 0u;

    __syncthreads();
    #pragma unroll
    for (int i = 0; i < 4; ++i)
      *(uint4*)&As[pl*72 + kb*32 + i*8] =
          make_uint4(raw[4*i], raw[4*i+1], raw[4*i+2], raw[4*i+3]);
    {
      int id = t;
      if (id < BN*8) {
        int oc = id >> 3, ch = id & 7;
        *(uint4*)&Bs[oc*72 + ch*8] = *(const uint4*)(Brow + (size_t)oc*K + k0 + ch*8);
      }
    }
    __syncthreads();

    #pragma unroll
    for (int ks = 0; ks < 2; ++ks) {
      bh8 af[2];
      #pragma unroll
      for (int fm = 0; fm < 2; ++fm)
        af[fm] = *(const bh8*)&As[(wv*32 + fm*16 + lr)*72 + ks*32 + lg*8];
      bh8 bf = *(const bh8*)&Bs[lr*72 + ks*32 + lg*8];
      #pragma unroll
      for (int fm = 0; fm < 2; ++fm)
        acc[fm] = __builtin_amdgcn_mfma_f32_16x16x32_bf16(af[fm], bf, acc[fm], 0, 0, 0);
    }
  }

  #pragma unroll
  for (int fm = 0; fm < 2; ++fm) {
    const int pq = mt*128 + wv*32 + fm*16 + lg*4;
    const int oc = lr;
    if (oc < 3) {
      const float bvv = bias[oc];
      const int nn = pq >> 14;
      const int hq = (pq >> 7) & 127, wq = pq & 127;
      const int qy = par >> 1, qx = par & 1;
      const int oh = 2*hq + qy;
      float* ob = outf + (((size_t)(nn*3 + oc)) << 16) + (oh << 8) + qx;
      ob[2*wq]     = acc[fm][0] + bvv;
      ob[2*wq + 2] = acc[fm][1] + bvv;
      ob[2*wq + 4] = acc[fm][2] + bvv;
      ob[2*wq + 6] = acc[fm][3] + bvv;
    }
  }
}

// ===========================================================================
// Weight preps
// ===========================================================================
__global__ void prep_enc(const float* __restrict__ ew1, const float* __restrict__ ew2,
                         const float* __restrict__ pvw, const float* __restrict__ emb,
                         float* bt1, u16* bt2h, u16* bt2l, float* btp,
                         u16* Ebh, u16* Ebl, float* enrm) {
  int i = blockIdx.x * 256 + threadIdx.x;
  if (i < 6144) {
    int k = i >> 7, oc = i & 127;
    bt1[i] = ew1[oc*48 + k];
  } else if ((i -= 6144) < 524288) {            // bt2h/l [oc][k'=dy*512+ic*4+dx]
    int oc = i >> 11, k = i & 2047;
    int dy = k >> 9, ic = (k >> 2) & 127, dx = k & 3;
    float v = ew2[oc*2048 + ic*16 + dy*4 + dx];
    u16 hi = f2bf(v);
    bt2h[i] = hi;
    bt2l[i] = f2bf(v - bf2f(hi));
  } else if ((i -= 524288) < 16384) {           // btp [k][64]
    int k = i >> 6, oc = i & 63;
    btp[i] = pvw[oc*256 + k];
  } else if ((i -= 16384) < 32768) {            // Ebh/Ebl [code][d] bf16 hi/lo
    float v = emb[i];
    u16 hi = f2bf(v);
    Ebh[i] = hi;
    Ebl[i] = f2bf(v - bf2f(hi));
  } else if ((i -= 32768) < 512) {              // ||e||^2 fp32
    float s = 0.f;
    const float* er = emb + (size_t)i * 64;
    #pragma unroll
    for (int d = 0; d < 64; ++d) s += er[d]*er[d];
    enrm[i] = s;
  }
}

__global__ void prep_dec(const float* __restrict__ qvw, const float* __restrict__ dw1,
                         const float* __restrict__ dw2,
                         u16* btq, u16* btd, u16* btd2) {
  int i = blockIdx.x * 256 + threadIdx.x;
  if (i < 147456) {                             // btq [oc][k=r*64+ic]
    int oc = i / 576, rem = i - oc*576, r = rem >> 6, ic = rem & 63;
    btq[i] = f2bf(qvw[oc*576 + ic*9 + r]);
  } else if ((i -= 147456) < 524288) {          // btd [par][oc][k=j*256+ic]
    int pr = i >> 17, oc = (i >> 10) & 127, j = (i >> 8) & 3, ic = i & 255;
    int py = pr >> 1, px = pr & 1, j1 = j >> 1, j0 = j & 1;
    btd[i] = f2bf(dw1[oc*4096 + ic*16 + (py + 2*j1)*4 + (px + 2*j0)]);
  } else if ((i -= 524288) < 32768) {           // btd2 [q][oc16][k=tap*128+ic]
    int q = i >> 13, oc = (i >> 9) & 15, tap = (i >> 7) & 3, ic = i & 127;
    int qy = q >> 1, qx = q & 1, j1 = tap >> 1, j0 = tap & 1;
    btd2[i] = (oc < 3) ? f2bf(dw2[oc*2048 + ic*16 + (qy + 2*j1)*4 + (qx + 2*j0)]) : (u16)0;
  }
}

// ===========================================================================
extern "C" void kernel_launch(void* const* d_in, const int* in_sizes, int n_in,
                              void* d_out, int out_size, void* d_ws, size_t ws_size,
                              hipStream_t stream) {
  (void)in_sizes; (void)n_in; (void)ws_size;
  const float* x   = (const float*)d_in[0];
  const float* ew1 = (const float*)d_in[1];
  const float* eb1 = (const float*)d_in[2];
  const float* ew2 = (const float*)d_in[3];
  const float* eb2 = (const float*)d_in[4];
  const float* pvw = (const float*)d_in[5];
  const float* pvb = (const float*)d_in[6];
  const float* emb = (const float*)d_in[7];
  const float* qvw = (const float*)d_in[8];
  const float* qvb = (const float*)d_in[9];
  const float* dw1 = (const float*)d_in[10];
  const float* db1 = (const float*)d_in[11];
  const float* dw2 = (const float*)d_in[12];
  const float* db2 = (const float*)d_in[13];
  float* out = (float*)d_out;

  char* ws = (char*)d_ws;
  uint*  h1u  = (uint*) (ws);                    // packed hi/lo parity planes, 67108864 B
  float* h2   = (float*)(ws + 67108864);         // [8,256,64,64] f32, 33554432 B
  uint*  qz32 = (uint*) (ws + 109051904);        // [8][32 c2][4096] packed, 4194304 B
  int*   hist = (int*)  (ws + 113246208);        // 2048 B
  float* lsum = (float*)(ws + 113248256);        // 64 B
  float* bt1  = (float*)(ws + 113248320);        // 24576 B
  float* btp  = (float*)(ws + 113272896);        // 65536 B
  u16*   bt2h = (u16*)  (ws + 113338432);        // 1048576 B
  u16*   bt2l = (u16*)  (ws + 114387008);        // 1048576 B
  u16*   btq  = (u16*)  (ws + 115435584);        // 294912 B
  u16*   btd  = (u16*)  (ws + 115730496);        // 1048576 B
  u16*   btd2 = (u16*)  (ws + 116779072);        // 65536 B
  u16*   Ebh  = (u16*)  (ws + 116844608);        // 65536 B (was Et)
  u16*   Ebl  = (u16*)  (ws + 116910144);        // 65536 B
  float* enrm = (float*)(ws + 116975680);        // 2048 B
  uint* g32  = (uint*)(ws + 67108864);  // [8][128 c2][4096] packed, overlays h2 (dead)
  uint* g232 = (uint*)ws;               // [8][4 par][64 c2][4096] packed, overlays h1u

  hipMemsetAsync(hist, 0, 2048 + 64, stream);
  prep_enc<<<2266, 256, 0, stream>>>(ew1, ew2, pvw, emb, bt1, bt2h, bt2l, btp, Ebh, Ebl, enrm);
  prep_dec<<<2752, 256, 0, stream>>>(qvw, dw1, dw2, btq, btd, btd2);

  conv1_f32<<<4096, 256, 0, stream>>>(x, bt1, eb1, h1u);
  conv2_mfma3<<<512, 256, 0, stream>>>(h1u, bt2h, bt2l, eb2, h2);

  prevq_vq<<<512, 256, 0, stream>>>(h2, btp, pvb, emb, Ebh, Ebl, enrm, qz32, hist, lsum);
  finalize_kernel<<<1, 512, 0, stream>>>(hist, lsum, out, out + (out_size - 1));

  dec_mfma128<M_POSTVQ> <<<512,  256, 0, stream>>>(qz32, btq, qvb, g32);
  dec_mfma128<M_DECONV1><<<1024, 256, 0, stream>>>(g32, btd, db1, g232);
  deconv2_mfma<<<4096, 256, 0, stream>>>(g232, btd2, db2, out + 1);
}

// Round 16
// 378.118 us; speedup vs baseline: 1.0567x; 1.0316x over previous
//
#include <hip/hip_runtime.h>
#include <math.h>

typedef unsigned short u16;
typedef unsigned int uint;
typedef __attribute__((ext_vector_type(8))) short bh8;   // 8 bf16 in 4 VGPRs
typedef __attribute__((ext_vector_type(4))) float f32x4;

#define DEV __device__ __forceinline__

DEV u16 f2bf(float x) {                       // fp32 -> bf16 RNE
  uint u = __builtin_bit_cast(uint, x);
  return (u16)((u + 0x7FFFu + ((u >> 16) & 1u)) >> 16);
}
DEV float bf2f(u16 h) { return __builtin_bit_cast(float, (uint)h << 16); }

// Bijective XCD-aware swizzle: 8 XCDs, contiguous chunk per XCD.
DEV int xcd_swz(int bid, int nb) {
  int c = nb >> 3;
  return (bid & 7) * c + (bid >> 3);
}

// ===========================================================================
// ENCODER stage 1: conv1 via bf16x3 split MFMA. BM=128 px, BN=128 oc,
// single K stage (K=48 padded to 64). A gathered fp32 -> hi/lo split inline.
// Emits h1 as packed-uint (hi|lo bf16) parity-split NCHW planes:
//   h1u[(n*128+oc)*16384 + ih*128 + (iw&1)*64 + (iw>>1)]
// ===========================================================================
__global__ __launch_bounds__(256, 2) void conv1_mfma3(const float* __restrict__ src,
                                                      const u16* __restrict__ B1h,
                                                      const u16* __restrict__ B1l,
                                                      const float* __restrict__ bias,
                                                      uint* __restrict__ outu) {
  __shared__ __align__(16) u16 Ah[128*72 + 32];
  __shared__ __align__(16) u16 Al[128*72 + 32];
  __shared__ __align__(16) u16 Bh[128*72 + 32];
  __shared__ __align__(16) u16 Bl[128*72 + 32];

  const int t = threadIdx.x;
  const int mt = xcd_swz((int)blockIdx.x, (int)gridDim.x);
  const int pl = t & 127, kb = t >> 7;
  const int p = mt*128 + pl;
  const int n = p >> 14, h = (p >> 7) & 127, w = p & 127;
  const int lane = t & 63, wv = t >> 6;
  const int lr = lane & 15, lg = lane >> 4;
  const int wm = wv & 1, wn = wv >> 1;

  // ---- A: gather 32 fp32 (24 real for kb=1), split hi/lo, pack pairs ----
  uint hi16[16], lo16[16];
  #pragma unroll
  for (int q = 0; q < 16; ++q) {
    uint hh = 0, ll = 0;
    #pragma unroll
    for (int e = 0; e < 2; ++e) {
      const int k = kb*32 + q*2 + e;
      float val = 0.f;
      if (k < 48) {
        const int ic = k >> 4, r = k & 15;
        const int ih = 2*h - 1 + (r >> 2), iw = 2*w - 1 + (r & 3);
        if ((unsigned)ih < 256u && (unsigned)iw < 256u)
          val = src[((n*3 + ic) << 16) + (ih << 8) + iw];
      }
      u16 hi = f2bf(val);
      u16 lo = f2bf(val - bf2f(hi));
      hh |= (uint)hi << (16*e);
      ll |= (uint)lo << (16*e);
    }
    hi16[q] = hh; lo16[q] = ll;
  }
  const int aw = pl*72 + kb*32;
  #pragma unroll
  for (int i = 0; i < 4; ++i) {
    *(uint4*)&Ah[aw + i*8] = *(uint4*)&hi16[4*i];
    *(uint4*)&Al[aw + i*8] = *(uint4*)&lo16[4*i];
  }
  // ---- B: 128 oc rows x 64 k hi/lo ----
  #pragma unroll
  for (int i = 0; i < 4; ++i) {
    int id = i*256 + t, oc = id >> 3, ch = id & 7;
    *(uint4*)&Bh[oc*72 + ch*8] = *(const uint4*)(B1h + (size_t)oc*64 + ch*8);
    *(uint4*)&Bl[oc*72 + ch*8] = *(const uint4*)(B1l + (size_t)oc*64 + ch*8);
  }
  __syncthreads();

  f32x4 acc[4][4];
  #pragma unroll
  for (int fm = 0; fm < 4; ++fm)
    #pragma unroll
    for (int fn = 0; fn < 4; ++fn)
      #pragma unroll
      for (int q = 0; q < 4; ++q) acc[fm][fn][q] = 0.f;

  #pragma unroll
  for (int ks = 0; ks < 2; ++ks) {
    bh8 afh[4], afl[4];
    #pragma unroll
    for (int fm = 0; fm < 4; ++fm) {
      const int r = (wm*64 + fm*16 + lr)*72 + ks*32 + lg*8;
      afh[fm] = *(const bh8*)&Ah[r];
      afl[fm] = *(const bh8*)&Al[r];
    }
    #pragma unroll
    for (int fn = 0; fn < 4; ++fn) {
      const int r = (wn*64 + fn*16 + lr)*72 + ks*32 + lg*8;
      bh8 bfh = *(const bh8*)&Bh[r];
      bh8 bfl = *(const bh8*)&Bl[r];
      #pragma unroll
      for (int fm = 0; fm < 4; ++fm) {
        acc[fm][fn] = __builtin_amdgcn_mfma_f32_16x16x32_bf16(afh[fm], bfh, acc[fm][fn], 0,0,0);
        acc[fm][fn] = __builtin_amdgcn_mfma_f32_16x16x32_bf16(afl[fm], bfh, acc[fm][fn], 0,0,0);
        acc[fm][fn] = __builtin_amdgcn_mfma_f32_16x16x32_bf16(afh[fm], bfl, acc[fm][fn], 0,0,0);
      }
    }
  }

  // ---- epilogue: bias+ReLU, hi/lo pack, parity-plane uint2 stores ----
  #pragma unroll
  for (int fm = 0; fm < 4; ++fm) {
    const int pq = mt*128 + wm*64 + fm*16 + lg*4;
    const int nn = pq >> 14, hh2 = (pq >> 7) & 127, ww = pq & 127;
    const int wh = ww >> 1;
    #pragma unroll
    for (int fn = 0; fn < 4; ++fn) {
      const int oc = wn*64 + fn*16 + lr;
      const float bv = bias[oc];
      uint pk[4];
      #pragma unroll
      for (int q = 0; q < 4; ++q) {
        float v = fmaxf(acc[fm][fn][q] + bv, 0.f);
        u16 hi = f2bf(v);
        u16 lo = f2bf(v - bf2f(hi));
        pk[q] = (uint)hi | ((uint)lo << 16);
      }
      uint* bp = outu + (size_t)(nn*128 + oc)*16384 + hh2*128;
      *(uint2*)(bp + wh)      = make_uint2(pk[0], pk[2]);   // parity 0
      *(uint2*)(bp + 64 + wh) = make_uint2(pk[1], pk[3]);   // parity 1
    }
  }
}

// ===========================================================================
// ENCODER stage 2: conv2 bf16x3 split MFMA. BM=128, BN=128, BK=64, grid 512.
// ===========================================================================
__global__ __launch_bounds__(256, 2) void conv2_mfma3(const uint* __restrict__ h1u,
                                                      const u16* __restrict__ Bh,
                                                      const u16* __restrict__ Bl,
                                                      const float* __restrict__ bias,
                                                      float* __restrict__ out) {
  __shared__ __align__(16) u16 Ah[128*72 + 32];
  __shared__ __align__(16) u16 Al[128*72 + 32];
  __shared__ __align__(16) u16 Bhs[128*72 + 32];
  __shared__ __align__(16) u16 Bls[128*72 + 32];

  const int t = threadIdx.x;
  const int bid = xcd_swz((int)blockIdx.x, (int)gridDim.x);
  const int nt = bid & 1, mt = bid >> 1;
  const int pl = t & 127, kb = t >> 7;
  const int p = mt*128 + pl;
  const int n = p >> 12, h = (p >> 6) & 63, w = p & 63;
  const int lane = t & 63, wv = t >> 6;
  const int lr = lane & 15, lg = lane >> 4;
  const int wm = wv & 1, wn = wv >> 1;

  int off[4]; uint mskd[4];
  off[0] = 64 + w - 1; mskd[0] = (w >= 1)  ? ~0u : 0u;
  off[1] = w;          mskd[1] = ~0u;
  off[2] = 64 + w;     mskd[2] = ~0u;
  off[3] = w + 1;      mskd[3] = (w <= 62) ? ~0u : 0u;

  f32x4 acc[4][4];
  #pragma unroll
  for (int fm = 0; fm < 4; ++fm)
    #pragma unroll
    for (int fn = 0; fn < 4; ++fn)
      #pragma unroll
      for (int q = 0; q < 4; ++q) acc[fm][fn][q] = 0.f;

  const int aw = pl*72 + kb*32;

  for (int k0 = 0; k0 < 2048; k0 += 64) {
    const int dy = k0 >> 9, icb = (k0 >> 2) & 127;   // ic block of 16 (8 per kb)
    const int ih = 2*h - 1 + dy;
    const uint mih = ((unsigned)ih < 128u) ? ~0u : 0u;
    const uint* pb = h1u + (size_t)(n*128 + icb + kb*8)*16384
                        + (((unsigned)ih < 128u) ? ih : 0)*128;
    uint m2[4];
    #pragma unroll
    for (int dx = 0; dx < 4; ++dx) m2[dx] = mskd[dx] & mih;

    uint raw[32];
    #pragma unroll
    for (int c = 0; c < 8; ++c)
      #pragma unroll
      for (int dx = 0; dx < 4; ++dx)
        raw[c*4 + dx] = pb[c*16384 + off[dx]] & m2[dx];

    uint hi16[16], lo16[16];
    #pragma unroll
    for (int q = 0; q < 16; ++q) {
      uint a = raw[2*q], b = raw[2*q+1];
      hi16[q] = (a & 0xffffu) | (b << 16);
      lo16[q] = (a >> 16) | (b & 0xffff0000u);
    }
    __syncthreads();
    #pragma unroll
    for (int i = 0; i < 4; ++i) {
      *(uint4*)&Ah[aw + i*8] = *(uint4*)&hi16[4*i];
      *(uint4*)&Al[aw + i*8] = *(uint4*)&lo16[4*i];
    }
    // B: 128 oc rows x 64 k, 4 uint4 per thread per buffer
    #pragma unroll
    for (int i = 0; i < 4; ++i) {
      int id = i*256 + t, oc = id >> 3, ch = id & 7;
      size_t bo = (size_t)(nt*128 + oc)*2048 + k0 + ch*8;
      *(uint4*)&Bhs[oc*72 + ch*8] = *(const uint4*)(Bh + bo);
      *(uint4*)&Bls[oc*72 + ch*8] = *(const uint4*)(Bl + bo);
    }
    __syncthreads();

    #pragma unroll
    for (int ks = 0; ks < 2; ++ks) {
      bh8 afh[4], afl[4];
      #pragma unroll
      for (int fm = 0; fm < 4; ++fm) {
        const int r = (wm*64 + fm*16 + lr)*72 + ks*32 + lg*8;
        afh[fm] = *(const bh8*)&Ah[r];
        afl[fm] = *(const bh8*)&Al[r];
      }
      #pragma unroll
      for (int fn = 0; fn < 4; ++fn) {
        const int r = (wn*64 + fn*16 + lr)*72 + ks*32 + lg*8;
        bh8 bfh = *(const bh8*)&Bhs[r];
        bh8 bfl = *(const bh8*)&Bls[r];
        #pragma unroll
        for (int fm = 0; fm < 4; ++fm) {
          acc[fm][fn] = __builtin_amdgcn_mfma_f32_16x16x32_bf16(afh[fm], bfh, acc[fm][fn], 0,0,0);
          acc[fm][fn] = __builtin_amdgcn_mfma_f32_16x16x32_bf16(afl[fm], bfh, acc[fm][fn], 0,0,0);
          acc[fm][fn] = __builtin_amdgcn_mfma_f32_16x16x32_bf16(afh[fm], bfl, acc[fm][fn], 0,0,0);
        }
      }
    }
  }

  #pragma unroll
  for (int fm = 0; fm < 4; ++fm) {
    const int pq = mt*128 + wm*64 + fm*16 + lg*4;
    const int nn = pq >> 12, hwq = pq & 4095;
    #pragma unroll
    for (int fn = 0; fn < 4; ++fn) {
      const int oc = nt*128 + wn*64 + fn*16 + lr;
      const float bv = bias[oc];
      float v0 = fmaxf(acc[fm][fn][0] + bv, 0.f);
      float v1 = fmaxf(acc[fm][fn][1] + bv, 0.f);
      float v2 = fmaxf(acc[fm][fn][2] + bv, 0.f);
      float v3 = fmaxf(acc[fm][fn][3] + bv, 0.f);
      *(float4*)(out + (((size_t)(nn*256 + oc)) << 12) + hwq) = make_float4(v0,v1,v2,v3);
    }
  }
}

// ===========================================================================
// FUSED prevq (fp32 GEMM) + VQ argmin (bf16x3 MFMA) + quantize/loss/hist.
// (verified r15, unchanged)
// ===========================================================================
__global__ __launch_bounds__(256, 2) void prevq_vq(const float* __restrict__ h2,
                                                   const float* __restrict__ btp,
                                                   const float* __restrict__ pvb,
                                                   const float* __restrict__ emb,
                                                   const u16* __restrict__ Ebh,
                                                   const u16* __restrict__ Ebl,
                                                   const float* __restrict__ enrm,
                                                   uint* __restrict__ qz32,
                                                   int* __restrict__ hist,
                                                   float* __restrict__ loss_sum) {
  __shared__ __align__(16) char SMEM[75776];
  float* Zs    = (float*)SMEM;                 // [64 d][68] fp32, 17408 B (persists)
  u16*   Zh    = (u16*)(SMEM + 17408);         // [64 px][72], 9216 B
  u16*   Zl    = (u16*)(SMEM + 26624);         // [64 px][72], 9216 B
  u16*   Eh    = (u16*)(SMEM + 35840);         // [128 code][72], 18432 B
  u16*   El    = (u16*)(SMEM + 54272);         // [128 code][72], 18432 B
  float* nrmS  = (float*)(SMEM + 72704);       // 128 f
  float* wredv = (float*)(SMEM + 73216);       // [4 wv][64 px]
  int*   wredi = (int*)(SMEM + 74240);         // [4 wv][64 px]
  int*   sIdx  = (int*)(SMEM + 75264);         // 64
  float* As    = (float*)(SMEM + 35840);       // phase1 alias, 4096 B
  float* Bs    = (float*)(SMEM + 35840 + 4096);// phase1 alias, 4096 B

  const int t = threadIdx.x;
  const int base = (int)blockIdx.x * 64;
  const int n = base >> 12, hwb = base & 4095;
  const int ti = t & 15, tj = t >> 4;

  // ---- Phase 1: prevq GEMM (BM=64, BN=64, K=256), exact fp32 ----
  {
    const int pl = t & 63, kb = t >> 6;
    const int hw = hwb + pl;
    float acc[4][4];
    #pragma unroll
    for (int i = 0; i < 4; ++i)
      #pragma unroll
      for (int j = 0; j < 4; ++j) acc[i][j] = 0.f;

    for (int k0 = 0; k0 < 256; k0 += 16) {
      #pragma unroll
      for (int jj = 0; jj < 4; ++jj) {
        int kr = jj*4 + kb;
        As[kr*64 + pl] = h2[((size_t)(n*256 + k0 + kr) << 12) + hw];
      }
      {
        int kr = t >> 4, c4 = t & 15;
        ((float4*)Bs)[kr*16 + c4] = *((const float4*)(btp + (size_t)(k0 + kr)*64) + c4);
      }
      __syncthreads();
      #pragma unroll
      for (int kk = 0; kk < 16; ++kk) {
        float a[4], b[4];
        *(float4*)&a[0] = *(const float4*)&As[kk*64 + ti*4];
        *(float4*)&b[0] = *(const float4*)&Bs[kk*64 + tj*4];
        #pragma unroll
        for (int i = 0; i < 4; ++i)
          #pragma unroll
          for (int j = 0; j < 4; ++j)
            acc[i][j] += a[i]*b[j];
      }
      __syncthreads();
    }
    // z -> Zs (fp32) and Zh/Zl (bf16 hi/lo, [px][d])
    #pragma unroll
    for (int j = 0; j < 4; ++j) {
      const int d = tj*4 + j;
      const float bvv = pvb[d];
      #pragma unroll
      for (int i = 0; i < 4; ++i) {
        const int px = ti*4 + i;
        float z = acc[i][j] + bvv;
        Zs[d*68 + px] = z;
        u16 h = f2bf(z);
        Zh[px*72 + d] = h;
        Zl[px*72 + d] = f2bf(z - bf2f(h));
      }
    }
  }

  // ---- Phase 2: argmin via bf16x3 MFMA over 4 chunks of 128 codes ----
  const int lane = t & 63, wv = t >> 6;
  const int lr = lane & 15, lg = lane >> 4;

  float bv2[4][4]; int bi2[4][4];          // [fm][q]: px = fm*16 + lg*4 + q
  #pragma unroll
  for (int fm = 0; fm < 4; ++fm)
    #pragma unroll
    for (int q = 0; q < 4; ++q) { bv2[fm][q] = 3.402823466e38f; bi2[fm][q] = 0; }

  for (int c = 0; c < 4; ++c) {
    __syncthreads();
    #pragma unroll
    for (int i = 0; i < 4; ++i) {
      int id = i*256 + t, row = id >> 3, ch = id & 7;
      *(uint4*)&Eh[row*72 + ch*8] = *(const uint4*)(Ebh + (size_t)(c*128 + row)*64 + ch*8);
      *(uint4*)&El[row*72 + ch*8] = *(const uint4*)(Ebl + (size_t)(c*128 + row)*64 + ch*8);
    }
    if (t < 128) nrmS[t] = enrm[c*128 + t];
    __syncthreads();

    f32x4 acc2[4][2];
    #pragma unroll
    for (int fm = 0; fm < 4; ++fm)
      #pragma unroll
      for (int fn = 0; fn < 2; ++fn)
        #pragma unroll
        for (int q = 0; q < 4; ++q) acc2[fm][fn][q] = 0.f;

    #pragma unroll
    for (int ks = 0; ks < 2; ++ks) {
      bh8 ah[4], al[4];
      #pragma unroll
      for (int fm = 0; fm < 4; ++fm) {
        const int r = (fm*16 + lr)*72 + ks*32 + lg*8;
        ah[fm] = *(const bh8*)&Zh[r];
        al[fm] = *(const bh8*)&Zl[r];
      }
      #pragma unroll
      for (int fn = 0; fn < 2; ++fn) {
        const int r = (wv*32 + fn*16 + lr)*72 + ks*32 + lg*8;
        bh8 bh_ = *(const bh8*)&Eh[r];
        bh8 bl_ = *(const bh8*)&El[r];
        #pragma unroll
        for (int fm = 0; fm < 4; ++fm) {
          acc2[fm][fn] = __builtin_amdgcn_mfma_f32_16x16x32_bf16(ah[fm], bh_, acc2[fm][fn], 0,0,0);
          acc2[fm][fn] = __builtin_amdgcn_mfma_f32_16x16x32_bf16(al[fm], bh_, acc2[fm][fn], 0,0,0);
          acc2[fm][fn] = __builtin_amdgcn_mfma_f32_16x16x32_bf16(ah[fm], bl_, acc2[fm][fn], 0,0,0);
        }
      }
    }
    // running argmin: dist = ||e||^2 - 2 z.e ; codes strictly increasing per slot
    #pragma unroll
    for (int fn = 0; fn < 2; ++fn) {
      const int code = c*128 + wv*32 + fn*16 + lr;
      const float nv = nrmS[wv*32 + fn*16 + lr];
      #pragma unroll
      for (int fm = 0; fm < 4; ++fm)
        #pragma unroll
        for (int q = 0; q < 4; ++q) {
          float d = nv - 2.f*acc2[fm][fn][q];
          if (d < bv2[fm][q]) { bv2[fm][q] = d; bi2[fm][q] = code; }
        }
    }
  }

  // per-wave reduce over lr lanes, then cross-wave via LDS
  #pragma unroll
  for (int fm = 0; fm < 4; ++fm)
    #pragma unroll
    for (int q = 0; q < 4; ++q) {
      float v = bv2[fm][q]; int ix = bi2[fm][q];
      #pragma unroll
      for (int m = 1; m < 16; m <<= 1) {
        float ov = __shfl_xor(v, m, 64);
        int   oi = __shfl_xor(ix, m, 64);
        if (ov < v || (ov == v && oi < ix)) { v = ov; ix = oi; }
      }
      if (lr == 0) {
        const int px = fm*16 + lg*4 + q;
        wredv[wv*64 + px] = v;
        wredi[wv*64 + px] = ix;
      }
    }
  __syncthreads();
  if (t < 64) {
    float best = 3.402823466e38f; int bid = 0x7fffffff;
    #pragma unroll
    for (int w2 = 0; w2 < 4; ++w2) {
      float v = wredv[w2*64 + t]; int ix = wredi[w2*64 + t];
      if (v < best || (v == best && ix < bid)) { best = v; bid = ix; }
    }
    sIdx[t] = bid;
  }
  __syncthreads();

  // ---- Phase 3: quantize (packed pairs) + loss + hist (exact fp32) ----
  const int px = t & 63, grp = t >> 6;
  const int ix = sIdx[px];
  const float* er = emb + (size_t)ix * 64 + grp*16;
  uint* qb = qz32 + ((size_t)(n*32 + grp*8))*4096 + hwb + px;
  float ls = 0.f;
  #pragma unroll
  for (int dp = 0; dp < 8; ++dp) {
    float e0 = er[2*dp], e1 = er[2*dp + 1];
    float z0 = Zs[(grp*16 + 2*dp)*68 + px];
    float z1 = Zs[(grp*16 + 2*dp + 1)*68 + px];
    float d0 = e0 - z0, d1 = e1 - z1;
    ls += d0*d0 + d1*d1;
    qb[(size_t)dp * 4096] = (uint)f2bf(e0) | ((uint)f2bf(e1) << 16);
  }
  if (t < 64) atomicAdd(&hist[ix], 1);
  #pragma unroll
  for (int o = 32; o; o >>= 1) ls += __shfl_down(ls, o, 64);
  if ((t & 63) == 0) atomicAdd(loss_sum, ls);
}

__global__ void finalize_kernel(const int* __restrict__ hist,
                                const float* __restrict__ loss_sum,
                                float* __restrict__ out_loss,
                                float* __restrict__ out_perp) {
  __shared__ float red[512];
  int t = threadIdx.x;
  float pr = (float)hist[t] * (1.f/32768.f);
  red[t] = pr * logf(pr + 1e-10f);
  __syncthreads();
  for (int s = 256; s; s >>= 1) {
    if (t < s) red[t] += red[t + s];
    __syncthreads();
  }
  if (t == 0) {
    out_loss[0] = 1.25f * loss_sum[0] * (1.f/2097152.f);
    out_perp[0] = expf(-red[0]);
  }
}

// ===========================================================================
// DECODER postvq/deconv1: 128x128 tile, BK=64, bf16 MFMA (r14/r15, verified).
// ===========================================================================
enum { M_POSTVQ, M_DECONV1, M_DECONV2 };

template<int MODE>
__global__ __launch_bounds__(256, 4) void dec_mfma128(const uint* __restrict__ srcu,
                                                      const u16* __restrict__ Bt,
                                                      const float* __restrict__ bias,
                                                      uint* __restrict__ out32) {
  constexpr int K = (MODE == M_POSTVQ) ? 576 : 1024;
  __shared__ __align__(16) u16 As[128*72 + 32];
  __shared__ __align__(16) u16 Bs[128*72 + 32];

  const int t = threadIdx.x;
  int bid = xcd_swz((int)blockIdx.x, (int)gridDim.x);
  int par = 0, nt = 0, mt;
  if constexpr (MODE == M_DECONV1) { par = bid & 3; mt = bid >> 2; }
  else                             { nt = bid & 1;  mt = bid >> 1; }
  const u16* Brow = Bt + (size_t)((MODE == M_DECONV1) ? par*128 : nt*128) * K;

  const int pl = t & 127, kb = t >> 7;
  const int p = mt*128 + pl;
  const int n = p >> 12, h = (p >> 6) & 63, w = p & 63;
  const int lane = t & 63, wv = t >> 6;
  const int lr = lane & 15, lg = lane >> 4;
  const int wm = wv & 1, wn = wv >> 1;

  f32x4 acc[4][4];
  #pragma unroll
  for (int fm = 0; fm < 4; ++fm)
    #pragma unroll
    for (int fn = 0; fn < 4; ++fn)
      #pragma unroll
      for (int q = 0; q < 4; ++q) acc[fm][fn][q] = 0.f;

  const int aw = pl*72 + kb*32;

  for (int k0 = 0; k0 < K; k0 += 64) {
    const uint* up; bool ok;
    if constexpr (MODE == M_POSTVQ) {
      int r = k0 >> 6, kh = r / 3, kw = r - 3*kh;
      int ih = h - 1 + kh, iw = w - 1 + kw;
      ok = ((unsigned)ih < 64u) && ((unsigned)iw < 64u);
      up = srcu + ((size_t)(n*32 + kb*16)) * 4096
                + (ok ? ((ih << 6) + iw) : 0);
    } else {
      int j = k0 >> 8, icb = k0 & 255;
      int j1 = j >> 1, j0 = j & 1;
      int py = par >> 1, px = par & 1;
      int ih = h + py - 1 + j1, iw = w + px - 1 + j0;
      ok = ((unsigned)ih < 64u) && ((unsigned)iw < 64u);
      up = srcu + ((size_t)(n*128 + (icb >> 1) + kb*16)) * 4096
                + (ok ? ((ih << 6) + iw) : 0);
    }
    uint raw[16];
    #pragma unroll
    for (int i = 0; i < 16; ++i)
      raw[i] = ok ? up[(size_t)i * 4096] : 0u;

    __syncthreads();
    #pragma unroll
    for (int i = 0; i < 4; ++i)
      *(uint4*)&As[aw + i*8] =
          make_uint4(raw[4*i], raw[4*i+1], raw[4*i+2], raw[4*i+3]);

    #pragma unroll
    for (int i = 0; i < 4; ++i) {
      int id = i*256 + t, oc = id >> 3, ch = id & 7;
      *(uint4*)&Bs[oc*72 + ch*8] = *(const uint4*)(Brow + (size_t)oc*K + k0 + ch*8);
    }
    __syncthreads();

    #pragma unroll
    for (int ks = 0; ks < 2; ++ks) {
      bh8 af[4];
      #pragma unroll
      for (int fm = 0; fm < 4; ++fm)
        af[fm] = *(const bh8*)&As[(wm*64 + fm*16 + lr)*72 + ks*32 + lg*8];
      #pragma unroll
      for (int fn = 0; fn < 4; ++fn) {
        bh8 bf = *(const bh8*)&Bs[(wn*64 + fn*16 + lr)*72 + ks*32 + lg*8];
        #pragma unroll
        for (int fm = 0; fm < 4; ++fm)
          acc[fm][fn] = __builtin_amdgcn_mfma_f32_16x16x32_bf16(af[fm], bf, acc[fm][fn], 0, 0, 0);
      }
    }
  }

  const bool evn = !(lr & 1);
  #pragma unroll
  for (int fm = 0; fm < 4; ++fm) {
    const int pq = mt*128 + wm*64 + fm*16 + lg*4;
    const int nn = pq >> 12, hwq = pq & 4095;
    #pragma unroll
    for (int fn = 0; fn < 4; ++fn) {
      const int oc = nt*128 + wn*64 + fn*16 + lr;
      const float bvv = bias[oc];
      float v[4];
      #pragma unroll
      for (int q = 0; q < 4; ++q) {
        v[q] = acc[fm][fn][q] + bvv;
        if constexpr (MODE == M_DECONV1) v[q] = fmaxf(v[q], 0.f);
      }
      float pv[4];
      #pragma unroll
      for (int q = 0; q < 4; ++q) pv[q] = __shfl_xor(v[q], 1, 64);
      uint pk[4];
      #pragma unroll
      for (int q = 0; q < 4; ++q) {
        u16 a = f2bf(evn ? v[q] : pv[q]);
        u16 b = f2bf(evn ? pv[q] : v[q]);
        pk[q] = (uint)a | ((uint)b << 16);
      }
      size_t pbase;
      if constexpr (MODE == M_POSTVQ)
        pbase = ((size_t)(nn*128 + (oc >> 1))) * 4096 + hwq;
      else
        pbase = ((size_t)((nn*4 + par)*64 + (oc >> 1))) * 4096 + hwq;
      if (evn) *(uint2*)(out32 + pbase)     = make_uint2(pk[0], pk[1]);
      else     *(uint2*)(out32 + pbase + 2) = make_uint2(pk[2], pk[3]);
    }
  }
}

// ===========================================================================
// DECODER deconv2 (BN=16, verified r13-r15 path, unchanged)
// ===========================================================================
__global__ __launch_bounds__(256, 4) void deconv2_mfma(const uint* __restrict__ srcu,
                                                       const u16* __restrict__ Bt,
                                                       const float* __restrict__ bias,
                                                       float* __restrict__ outf) {
  constexpr int K = 512, BN = 16;
  __shared__ __align__(16) u16 As[128 * 72];
  __shared__ __align__(16) u16 Bs[BN * 72];

  const int t = threadIdx.x;
  int bid = xcd_swz((int)blockIdx.x, (int)gridDim.x);
  int par = bid & 3; bid >>= 2;
  const int mt = bid;
  const u16* Brow = Bt + (size_t)par * BN * K;

  const int pl = t & 127, kb = t >> 7;
  const int p = mt * 128 + pl;
  const int n = p >> 14, h = (p >> 7) & 127, w = p & 127;

  const int lane = t & 63, wv = t >> 6;
  const int lr = lane & 15, lg = lane >> 4;

  f32x4 acc[2];
  #pragma unroll
  for (int fm = 0; fm < 2; ++fm)
    #pragma unroll
    for (int q = 0; q < 4; ++q) acc[fm][q] = 0.f;

  for (int k0 = 0; k0 < K; k0 += 64) {
    int tap = k0 >> 7, icb = k0 & 127;
    int j1 = tap >> 1, j0 = tap & 1;
    int qy = par >> 1, qx = par & 1;
    int ih = h - 1 + qy + j1, iw = w - 1 + qx + j0;
    bool ok = ((unsigned)ih < 128u) && ((unsigned)iw < 128u);
    int ipar = ((ih & 1) << 1) | (iw & 1);
    const uint* up = srcu + ((size_t)((n*4 + ipar)*64 + (icb >> 1) + kb*16)) * 4096
                          + (ok ? (((ih >> 1) << 6) + (iw >> 1)) : 0);
    uint raw[16];
    #pragma unroll
    for (int i = 0; i < 16; ++i)
      raw[i] = ok ? up[(size_t)i * 4096] : 0u;

    __syncthreads();
    #pragma unroll
    for (int i = 0; i < 4; ++i)
      *(uint4*)&As[pl*72 + kb*32 + i*8] =
          make_uint4(raw[4*i], raw[4*i+1], raw[4*i+2], raw[4*i+3]);
    {
      int id = t;
      if (id < BN*8) {
        int oc = id >> 3, ch = id & 7;
        *(uint4*)&Bs[oc*72 + ch*8] = *(const uint4*)(Brow + (size_t)oc*K + k0 + ch*8);
      }
    }
    __syncthreads();

    #pragma unroll
    for (int ks = 0; ks < 2; ++ks) {
      bh8 af[2];
      #pragma unroll
      for (int fm = 0; fm < 2; ++fm)
        af[fm] = *(const bh8*)&As[(wv*32 + fm*16 + lr)*72 + ks*32 + lg*8];
      bh8 bf = *(const bh8*)&Bs[lr*72 + ks*32 + lg*8];
      #pragma unroll
      for (int fm = 0; fm < 2; ++fm)
        acc[fm] = __builtin_amdgcn_mfma_f32_16x16x32_bf16(af[fm], bf, acc[fm], 0, 0, 0);
    }
  }

  #pragma unroll
  for (int fm = 0; fm < 2; ++fm) {
    const int pq = mt*128 + wv*32 + fm*16 + lg*4;
    const int oc = lr;
    if (oc < 3) {
      const float bvv = bias[oc];
      const int nn = pq >> 14;
      const int hq = (pq >> 7) & 127, wq = pq & 127;
      const int qy = par >> 1, qx = par & 1;
      const int oh = 2*hq + qy;
      float* ob = outf + (((size_t)(nn*3 + oc)) << 16) + (oh << 8) + qx;
      ob[2*wq]     = acc[fm][0] + bvv;
      ob[2*wq + 2] = acc[fm][1] + bvv;
      ob[2*wq + 4] = acc[fm][2] + bvv;
      ob[2*wq + 6] = acc[fm][3] + bvv;
    }
  }
}

// ===========================================================================
// Single prep kernel: all weight transforms + hist/lsum zeroing
// ===========================================================================
__global__ void prep_all(const float* __restrict__ ew1, const float* __restrict__ ew2,
                         const float* __restrict__ pvw, const float* __restrict__ emb,
                         const float* __restrict__ qvw, const float* __restrict__ dw1,
                         const float* __restrict__ dw2,
                         u16* bt1h, u16* bt1l, u16* bt2h, u16* bt2l, float* btp,
                         u16* Ebh, u16* Ebl, float* enrm,
                         u16* btq, u16* btd, u16* btd2,
                         int* hist, float* lsum) {
  int i = blockIdx.x * 256 + threadIdx.x;
  if (i < 8192) {                               // bt1h/l [oc 128][k 64], k=ic*16+r
    int oc = i >> 6, k = i & 63;
    float v = (k < 48) ? ew1[oc*48 + k] : 0.f;
    u16 hi = f2bf(v);
    bt1h[i] = hi;
    bt1l[i] = f2bf(v - bf2f(hi));
  } else if ((i -= 8192) < 524288) {            // bt2h/l [oc][k'=dy*512+ic*4+dx]
    int oc = i >> 11, k = i & 2047;
    int dy = k >> 9, ic = (k >> 2) & 127, dx = k & 3;
    float v = ew2[oc*2048 + ic*16 + dy*4 + dx];
    u16 hi = f2bf(v);
    bt2h[i] = hi;
    bt2l[i] = f2bf(v - bf2f(hi));
  } else if ((i -= 524288) < 16384) {           // btp [k][64] fp32
    int k = i >> 6, oc = i & 63;
    btp[i] = pvw[oc*256 + k];
  } else if ((i -= 16384) < 32768) {            // Ebh/Ebl [code][d] bf16 hi/lo
    float v = emb[i];
    u16 hi = f2bf(v);
    Ebh[i] = hi;
    Ebl[i] = f2bf(v - bf2f(hi));
  } else if ((i -= 32768) < 512) {              // ||e||^2 fp32
    float s = 0.f;
    const float* er = emb + (size_t)i * 64;
    #pragma unroll
    for (int d = 0; d < 64; ++d) s += er[d]*er[d];
    enrm[i] = s;
  } else if ((i -= 512) < 147456) {             // btq [oc][k=r*64+ic]
    int oc = i / 576, rem = i - oc*576, r = rem >> 6, ic = rem & 63;
    btq[i] = f2bf(qvw[oc*576 + ic*9 + r]);
  } else if ((i -= 147456) < 524288) {          // btd [par][oc][k=j*256+ic]
    int pr = i >> 17, oc = (i >> 10) & 127, j = (i >> 8) & 3, ic = i & 255;
    int py = pr >> 1, px = pr & 1, j1 = j >> 1, j0 = j & 1;
    btd[i] = f2bf(dw1[oc*4096 + ic*16 + (py + 2*j1)*4 + (px + 2*j0)]);
  } else if ((i -= 524288) < 32768) {           // btd2 [q][oc16][k=tap*128+ic]
    int q = i >> 13, oc = (i >> 9) & 15, tap = (i >> 7) & 3, ic = i & 127;
    int qy = q >> 1, qx = q & 1, j1 = tap >> 1, j0 = tap & 1;
    btd2[i] = (oc < 3) ? f2bf(dw2[oc*2048 + ic*16 + (qy + 2*j1)*4 + (qx + 2*j0)]) : (u16)0;
  } else if ((i -= 32768) < 528) {              // zero hist (512) + lsum (16 f)
    if (i < 512) hist[i] = 0;
    else         lsum[i - 512] = 0.f;
  }
}

// ===========================================================================
extern "C" void kernel_launch(void* const* d_in, const int* in_sizes, int n_in,
                              void* d_out, int out_size, void* d_ws, size_t ws_size,
                              hipStream_t stream) {
  (void)in_sizes; (void)n_in; (void)ws_size;
  const float* x   = (const float*)d_in[0];
  const float* ew1 = (const float*)d_in[1];
  const float* eb1 = (const float*)d_in[2];
  const float* ew2 = (const float*)d_in[3];
  const float* eb2 = (const float*)d_in[4];
  const float* pvw = (const float*)d_in[5];
  const float* pvb = (const float*)d_in[6];
  const float* emb = (const float*)d_in[7];
  const float* qvw = (const float*)d_in[8];
  const float* qvb = (const float*)d_in[9];
  const float* dw1 = (const float*)d_in[10];
  const float* db1 = (const float*)d_in[11];
  const float* dw2 = (const float*)d_in[12];
  const float* db2 = (const float*)d_in[13];
  float* out = (float*)d_out;

  char* ws = (char*)d_ws;
  uint*  h1u  = (uint*) (ws);                    // packed hi/lo parity planes, 67108864 B
  float* h2   = (float*)(ws + 67108864);         // [8,256,64,64] f32, 33554432 B
  uint*  qz32 = (uint*) (ws + 109051904);        // [8][32 c2][4096] packed, 4194304 B
  int*   hist = (int*)  (ws + 113246208);        // 2048 B
  float* lsum = (float*)(ws + 113248256);        // 64 B
  u16*   bt1h = (u16*)  (ws + 113248320);        // 16384 B
  u16*   bt1l = (u16*)  (ws + 113264704);        // 16384 B
  float* btp  = (float*)(ws + 113281088);        // 65536 B
  u16*   bt2h = (u16*)  (ws + 113346624);        // 1048576 B
  u16*   bt2l = (u16*)  (ws + 114395200);        // 1048576 B
  u16*   btq  = (u16*)  (ws + 115443776);        // 294912 B
  u16*   btd  = (u16*)  (ws + 115738688);        // 1048576 B
  u16*   btd2 = (u16*)  (ws + 116787264);        // 65536 B
  u16*   Ebh  = (u16*)  (ws + 116852800);        // 65536 B
  u16*   Ebl  = (u16*)  (ws + 116918336);        // 65536 B
  float* enrm = (float*)(ws + 116983872);        // 2048 B
  uint* g32  = (uint*)(ws + 67108864);  // [8][128 c2][4096] packed, overlays h2 (dead)
  uint* g232 = (uint*)ws;               // [8][4 par][64 c2][4096] packed, overlays h1u

  prep_all<<<5029, 256, 0, stream>>>(ew1, ew2, pvw, emb, qvw, dw1, dw2,
                                     bt1h, bt1l, bt2h, bt2l, btp,
                                     Ebh, Ebl, enrm, btq, btd, btd2, hist, lsum);

  conv1_mfma3<<<1024, 256, 0, stream>>>(x, bt1h, bt1l, eb1, h1u);
  conv2_mfma3<<<512, 256, 0, stream>>>(h1u, bt2h, bt2l, eb2, h2);

  prevq_vq<<<512, 256, 0, stream>>>(h2, btp, pvb, emb, Ebh, Ebl, enrm, qz32, hist, lsum);
  finalize_kernel<<<1, 512, 0, stream>>>(hist, lsum, out, out + (out_size - 1));

  dec_mfma128<M_POSTVQ> <<<512,  256, 0, stream>>>(qz32, btq, qvb, g32);
  dec_mfma128<M_DECONV1><<<1024, 256, 0, stream>>>(g32, btd, db1, g232);
  deconv2_mfma<<<4096, 256, 0, stream>>>(g232, btd2, db2, out + 1);
}

// Round 17
// 368.729 us; speedup vs baseline: 1.0836x; 1.0255x over previous
//
#include <hip/hip_runtime.h>
#include <math.h>

typedef unsigned short u16;
typedef unsigned int uint;
typedef __attribute__((ext_vector_type(8))) short bh8;   // 8 bf16 in 4 VGPRs
typedef __attribute__((ext_vector_type(4))) float f32x4;

#define DEV __device__ __forceinline__

DEV u16 f2bf(float x) {                       // fp32 -> bf16 RNE
  uint u = __builtin_bit_cast(uint, x);
  return (u16)((u + 0x7FFFu + ((u >> 16) & 1u)) >> 16);
}
DEV float bf2f(u16 h) { return __builtin_bit_cast(float, (uint)h << 16); }

// Bijective XCD-aware swizzle: 8 XCDs, contiguous chunk per XCD.
DEV int xcd_swz(int bid, int nb) {
  int c = nb >> 3;
  return (bid & 7) * c + (bid >> 3);
}

// ===========================================================================
// ENCODER stage 1: conv1 via bf16x3 split MFMA (r16 verified, unchanged).
// ===========================================================================
__global__ __launch_bounds__(256, 2) void conv1_mfma3(const float* __restrict__ src,
                                                      const u16* __restrict__ B1h,
                                                      const u16* __restrict__ B1l,
                                                      const float* __restrict__ bias,
                                                      uint* __restrict__ outu) {
  __shared__ __align__(16) u16 Ah[128*72 + 32];
  __shared__ __align__(16) u16 Al[128*72 + 32];
  __shared__ __align__(16) u16 Bh[128*72 + 32];
  __shared__ __align__(16) u16 Bl[128*72 + 32];

  const int t = threadIdx.x;
  const int mt = xcd_swz((int)blockIdx.x, (int)gridDim.x);
  const int pl = t & 127, kb = t >> 7;
  const int p = mt*128 + pl;
  const int n = p >> 14, h = (p >> 7) & 127, w = p & 127;
  const int lane = t & 63, wv = t >> 6;
  const int lr = lane & 15, lg = lane >> 4;
  const int wm = wv & 1, wn = wv >> 1;

  uint hi16[16], lo16[16];
  #pragma unroll
  for (int q = 0; q < 16; ++q) {
    uint hh = 0, ll = 0;
    #pragma unroll
    for (int e = 0; e < 2; ++e) {
      const int k = kb*32 + q*2 + e;
      float val = 0.f;
      if (k < 48) {
        const int ic = k >> 4, r = k & 15;
        const int ih = 2*h - 1 + (r >> 2), iw = 2*w - 1 + (r & 3);
        if ((unsigned)ih < 256u && (unsigned)iw < 256u)
          val = src[((n*3 + ic) << 16) + (ih << 8) + iw];
      }
      u16 hi = f2bf(val);
      u16 lo = f2bf(val - bf2f(hi));
      hh |= (uint)hi << (16*e);
      ll |= (uint)lo << (16*e);
    }
    hi16[q] = hh; lo16[q] = ll;
  }
  const int aw = pl*72 + kb*32;
  #pragma unroll
  for (int i = 0; i < 4; ++i) {
    *(uint4*)&Ah[aw + i*8] = *(uint4*)&hi16[4*i];
    *(uint4*)&Al[aw + i*8] = *(uint4*)&lo16[4*i];
  }
  #pragma unroll
  for (int i = 0; i < 4; ++i) {
    int id = i*256 + t, oc = id >> 3, ch = id & 7;
    *(uint4*)&Bh[oc*72 + ch*8] = *(const uint4*)(B1h + (size_t)oc*64 + ch*8);
    *(uint4*)&Bl[oc*72 + ch*8] = *(const uint4*)(B1l + (size_t)oc*64 + ch*8);
  }
  __syncthreads();

  f32x4 acc[4][4];
  #pragma unroll
  for (int fm = 0; fm < 4; ++fm)
    #pragma unroll
    for (int fn = 0; fn < 4; ++fn)
      #pragma unroll
      for (int q = 0; q < 4; ++q) acc[fm][fn][q] = 0.f;

  #pragma unroll
  for (int ks = 0; ks < 2; ++ks) {
    bh8 afh[4], afl[4];
    #pragma unroll
    for (int fm = 0; fm < 4; ++fm) {
      const int r = (wm*64 + fm*16 + lr)*72 + ks*32 + lg*8;
      afh[fm] = *(const bh8*)&Ah[r];
      afl[fm] = *(const bh8*)&Al[r];
    }
    #pragma unroll
    for (int fn = 0; fn < 4; ++fn) {
      const int r = (wn*64 + fn*16 + lr)*72 + ks*32 + lg*8;
      bh8 bfh = *(const bh8*)&Bh[r];
      bh8 bfl = *(const bh8*)&Bl[r];
      #pragma unroll
      for (int fm = 0; fm < 4; ++fm) {
        acc[fm][fn] = __builtin_amdgcn_mfma_f32_16x16x32_bf16(afh[fm], bfh, acc[fm][fn], 0,0,0);
        acc[fm][fn] = __builtin_amdgcn_mfma_f32_16x16x32_bf16(afl[fm], bfh, acc[fm][fn], 0,0,0);
        acc[fm][fn] = __builtin_amdgcn_mfma_f32_16x16x32_bf16(afh[fm], bfl, acc[fm][fn], 0,0,0);
      }
    }
  }

  #pragma unroll
  for (int fm = 0; fm < 4; ++fm) {
    const int pq = mt*128 + wm*64 + fm*16 + lg*4;
    const int nn = pq >> 14, hh2 = (pq >> 7) & 127, ww = pq & 127;
    const int wh = ww >> 1;
    #pragma unroll
    for (int fn = 0; fn < 4; ++fn) {
      const int oc = wn*64 + fn*16 + lr;
      const float bv = bias[oc];
      uint pk[4];
      #pragma unroll
      for (int q = 0; q < 4; ++q) {
        float v = fmaxf(acc[fm][fn][q] + bv, 0.f);
        u16 hi = f2bf(v);
        u16 lo = f2bf(v - bf2f(hi));
        pk[q] = (uint)hi | ((uint)lo << 16);
      }
      uint* bp = outu + (size_t)(nn*128 + oc)*16384 + hh2*128;
      *(uint2*)(bp + wh)      = make_uint2(pk[0], pk[2]);   // parity 0
      *(uint2*)(bp + 64 + wh) = make_uint2(pk[1], pk[3]);   // parity 1
    }
  }
}

// ===========================================================================
// ENCODER stage 2: conv2 bf16x3 split MFMA. BM=128, BN=128, BK=64, grid 512.
// NOW emits h2 as packed (hi|lo) uints: h2u[n*256+oc][hw 4096].
// ===========================================================================
__global__ __launch_bounds__(256, 2) void conv2_mfma3(const uint* __restrict__ h1u,
                                                      const u16* __restrict__ Bh,
                                                      const u16* __restrict__ Bl,
                                                      const float* __restrict__ bias,
                                                      uint* __restrict__ outh2) {
  __shared__ __align__(16) u16 Ah[128*72 + 32];
  __shared__ __align__(16) u16 Al[128*72 + 32];
  __shared__ __align__(16) u16 Bhs[128*72 + 32];
  __shared__ __align__(16) u16 Bls[128*72 + 32];

  const int t = threadIdx.x;
  const int bid = xcd_swz((int)blockIdx.x, (int)gridDim.x);
  const int nt = bid & 1, mt = bid >> 1;
  const int pl = t & 127, kb = t >> 7;
  const int p = mt*128 + pl;
  const int n = p >> 12, h = (p >> 6) & 63, w = p & 63;
  const int lane = t & 63, wv = t >> 6;
  const int lr = lane & 15, lg = lane >> 4;
  const int wm = wv & 1, wn = wv >> 1;

  int off[4]; uint mskd[4];
  off[0] = 64 + w - 1; mskd[0] = (w >= 1)  ? ~0u : 0u;
  off[1] = w;          mskd[1] = ~0u;
  off[2] = 64 + w;     mskd[2] = ~0u;
  off[3] = w + 1;      mskd[3] = (w <= 62) ? ~0u : 0u;

  f32x4 acc[4][4];
  #pragma unroll
  for (int fm = 0; fm < 4; ++fm)
    #pragma unroll
    for (int fn = 0; fn < 4; ++fn)
      #pragma unroll
      for (int q = 0; q < 4; ++q) acc[fm][fn][q] = 0.f;

  const int aw = pl*72 + kb*32;

  for (int k0 = 0; k0 < 2048; k0 += 64) {
    const int dy = k0 >> 9, icb = (k0 >> 2) & 127;
    const int ih = 2*h - 1 + dy;
    const uint mih = ((unsigned)ih < 128u) ? ~0u : 0u;
    const uint* pb = h1u + (size_t)(n*128 + icb + kb*8)*16384
                        + (((unsigned)ih < 128u) ? ih : 0)*128;
    uint m2[4];
    #pragma unroll
    for (int dx = 0; dx < 4; ++dx) m2[dx] = mskd[dx] & mih;

    uint raw[32];
    #pragma unroll
    for (int c = 0; c < 8; ++c)
      #pragma unroll
      for (int dx = 0; dx < 4; ++dx)
        raw[c*4 + dx] = pb[c*16384 + off[dx]] & m2[dx];

    uint hi16[16], lo16[16];
    #pragma unroll
    for (int q = 0; q < 16; ++q) {
      uint a = raw[2*q], b = raw[2*q+1];
      hi16[q] = (a & 0xffffu) | (b << 16);
      lo16[q] = (a >> 16) | (b & 0xffff0000u);
    }
    __syncthreads();
    #pragma unroll
    for (int i = 0; i < 4; ++i) {
      *(uint4*)&Ah[aw + i*8] = *(uint4*)&hi16[4*i];
      *(uint4*)&Al[aw + i*8] = *(uint4*)&lo16[4*i];
    }
    #pragma unroll
    for (int i = 0; i < 4; ++i) {
      int id = i*256 + t, oc = id >> 3, ch = id & 7;
      size_t bo = (size_t)(nt*128 + oc)*2048 + k0 + ch*8;
      *(uint4*)&Bhs[oc*72 + ch*8] = *(const uint4*)(Bh + bo);
      *(uint4*)&Bls[oc*72 + ch*8] = *(const uint4*)(Bl + bo);
    }
    __syncthreads();

    #pragma unroll
    for (int ks = 0; ks < 2; ++ks) {
      bh8 afh[4], afl[4];
      #pragma unroll
      for (int fm = 0; fm < 4; ++fm) {
        const int r = (wm*64 + fm*16 + lr)*72 + ks*32 + lg*8;
        afh[fm] = *(const bh8*)&Ah[r];
        afl[fm] = *(const bh8*)&Al[r];
      }
      #pragma unroll
      for (int fn = 0; fn < 4; ++fn) {
        const int r = (wn*64 + fn*16 + lr)*72 + ks*32 + lg*8;
        bh8 bfh = *(const bh8*)&Bhs[r];
        bh8 bfl = *(const bh8*)&Bls[r];
        #pragma unroll
        for (int fm = 0; fm < 4; ++fm) {
          acc[fm][fn] = __builtin_amdgcn_mfma_f32_16x16x32_bf16(afh[fm], bfh, acc[fm][fn], 0,0,0);
          acc[fm][fn] = __builtin_amdgcn_mfma_f32_16x16x32_bf16(afl[fm], bfh, acc[fm][fn], 0,0,0);
          acc[fm][fn] = __builtin_amdgcn_mfma_f32_16x16x32_bf16(afh[fm], bfl, acc[fm][fn], 0,0,0);
        }
      }
    }
  }

  #pragma unroll
  for (int fm = 0; fm < 4; ++fm) {
    const int pq = mt*128 + wm*64 + fm*16 + lg*4;
    const int nn = pq >> 12, hwq = pq & 4095;
    #pragma unroll
    for (int fn = 0; fn < 4; ++fn) {
      const int oc = nt*128 + wn*64 + fn*16 + lr;
      const float bv = bias[oc];
      uint pk[4];
      #pragma unroll
      for (int q = 0; q < 4; ++q) {
        float v = fmaxf(acc[fm][fn][q] + bv, 0.f);
        u16 hi = f2bf(v);
        u16 lo = f2bf(v - bf2f(hi));
        pk[q] = (uint)hi | ((uint)lo << 16);
      }
      *(uint4*)(outh2 + (((size_t)(nn*256 + oc)) << 12) + hwq) =
          make_uint4(pk[0], pk[1], pk[2], pk[3]);
    }
  }
}

// ===========================================================================
// FUSED prevq (bf16x3 MFMA) + VQ argmin (bf16x3 MFMA) + quantize/loss/hist.
// 64 px/block. Phase1: z = h2 @ pvw + pvb via hi/lo split (err ~2^-17).
// Phase3 loss uses the fp32 z from phase1 (Zs).
// ===========================================================================
__global__ __launch_bounds__(256, 2) void prevq_vq(const uint* __restrict__ h2u,
                                                   const u16* __restrict__ btph,
                                                   const u16* __restrict__ btpl,
                                                   const float* __restrict__ pvb,
                                                   const float* __restrict__ emb,
                                                   const u16* __restrict__ Ebh,
                                                   const u16* __restrict__ Ebl,
                                                   const float* __restrict__ enrm,
                                                   uint* __restrict__ qz32,
                                                   int* __restrict__ hist,
                                                   float* __restrict__ loss_sum) {
  __shared__ __align__(16) char SMEM[75776];
  float* Zs    = (float*)SMEM;                 // [64 d][68] fp32, 17408 B (persists)
  u16*   Zh    = (u16*)(SMEM + 17408);         // [64 px][72], 9216 B
  u16*   Zl    = (u16*)(SMEM + 26624);         // [64 px][72], 9216 B
  // phase1 aliases (region reused by Eh/El in phase 2):
  u16*   A1h   = (u16*)(SMEM + 35840);         // [64 px][72]
  u16*   A1l   = (u16*)(SMEM + 45056);
  u16*   B1h   = (u16*)(SMEM + 54272);         // [64 d][72]
  u16*   B1l   = (u16*)(SMEM + 63488);
  // phase2:
  u16*   Eh    = (u16*)(SMEM + 35840);         // [128 code][72], 18432 B
  u16*   El    = (u16*)(SMEM + 54272);         // [128 code][72], 18432 B
  float* nrmS  = (float*)(SMEM + 72704);       // 128 f
  float* wredv = (float*)(SMEM + 73216);       // [4 wv][64 px]
  int*   wredi = (int*)(SMEM + 74240);         // [4 wv][64 px]
  int*   sIdx  = (int*)(SMEM + 75264);         // 64

  const int t = threadIdx.x;
  const int base = (int)blockIdx.x * 64;
  const int n = base >> 12, hwb = base & 4095;
  const int lane = t & 63, wv = t >> 6;
  const int lr = lane & 15, lg = lane >> 4;

  // ---- Phase 1: prevq GEMM via bf16x3 MFMA (M=64 px, N=64 d, K=256) ----
  {
    const int px = t & 63, kb = t >> 6;        // kb: 16-ic block
    f32x4 acc1[4];
    #pragma unroll
    for (int fm = 0; fm < 4; ++fm)
      #pragma unroll
      for (int q = 0; q < 4; ++q) acc1[fm][q] = 0.f;

    for (int k0 = 0; k0 < 256; k0 += 64) {
      const uint* pb = h2u + ((size_t)(n*256 + k0 + kb*16)) * 4096 + hwb + px;
      uint raw[16];
      #pragma unroll
      for (int c = 0; c < 16; ++c) raw[c] = pb[(size_t)c * 4096];
      uint hi8[8], lo8[8];
      #pragma unroll
      for (int q = 0; q < 8; ++q) {
        uint a = raw[2*q], b = raw[2*q+1];
        hi8[q] = (a & 0xffffu) | (b << 16);
        lo8[q] = (a >> 16) | (b & 0xffff0000u);
      }
      __syncthreads();
      const int aw = px*72 + kb*16;
      *(uint4*)&A1h[aw]     = *(uint4*)&hi8[0];
      *(uint4*)&A1h[aw + 8] = *(uint4*)&hi8[4];
      *(uint4*)&A1l[aw]     = *(uint4*)&lo8[0];
      *(uint4*)&A1l[aw + 8] = *(uint4*)&lo8[4];
      #pragma unroll
      for (int i = 0; i < 2; ++i) {
        int id = i*256 + t, d = id >> 3, ch = id & 7;
        *(uint4*)&B1h[d*72 + ch*8] = *(const uint4*)(btph + (size_t)d*256 + k0 + ch*8);
        *(uint4*)&B1l[d*72 + ch*8] = *(const uint4*)(btpl + (size_t)d*256 + k0 + ch*8);
      }
      __syncthreads();

      #pragma unroll
      for (int ks = 0; ks < 2; ++ks) {
        bh8 bh_ = *(const bh8*)&B1h[(wv*16 + lr)*72 + ks*32 + lg*8];
        bh8 bl_ = *(const bh8*)&B1l[(wv*16 + lr)*72 + ks*32 + lg*8];
        #pragma unroll
        for (int fm = 0; fm < 4; ++fm) {
          bh8 ah = *(const bh8*)&A1h[(fm*16 + lr)*72 + ks*32 + lg*8];
          bh8 al = *(const bh8*)&A1l[(fm*16 + lr)*72 + ks*32 + lg*8];
          acc1[fm] = __builtin_amdgcn_mfma_f32_16x16x32_bf16(ah, bh_, acc1[fm], 0,0,0);
          acc1[fm] = __builtin_amdgcn_mfma_f32_16x16x32_bf16(al, bh_, acc1[fm], 0,0,0);
          acc1[fm] = __builtin_amdgcn_mfma_f32_16x16x32_bf16(ah, bl_, acc1[fm], 0,0,0);
        }
      }
    }
    // z epilogue: d = wv*16+lr, px = fm*16 + lg*4 + q
    const int d = wv*16 + lr;
    const float bvv = pvb[d];
    #pragma unroll
    for (int fm = 0; fm < 4; ++fm)
      #pragma unroll
      for (int q = 0; q < 4; ++q) {
        const int pxo = fm*16 + lg*4 + q;
        float z = acc1[fm][q] + bvv;
        Zs[d*68 + pxo] = z;
        u16 hh = f2bf(z);
        Zh[pxo*72 + d] = hh;
        Zl[pxo*72 + d] = f2bf(z - bf2f(hh));
      }
  }

  // ---- Phase 2: argmin via bf16x3 MFMA over 4 chunks of 128 codes ----
  float bv2[4][4]; int bi2[4][4];          // [fm][q]: px = fm*16 + lg*4 + q
  #pragma unroll
  for (int fm = 0; fm < 4; ++fm)
    #pragma unroll
    for (int q = 0; q < 4; ++q) { bv2[fm][q] = 3.402823466e38f; bi2[fm][q] = 0; }

  for (int c = 0; c < 4; ++c) {
    __syncthreads();
    #pragma unroll
    for (int i = 0; i < 4; ++i) {
      int id = i*256 + t, row = id >> 3, ch = id & 7;
      *(uint4*)&Eh[row*72 + ch*8] = *(const uint4*)(Ebh + (size_t)(c*128 + row)*64 + ch*8);
      *(uint4*)&El[row*72 + ch*8] = *(const uint4*)(Ebl + (size_t)(c*128 + row)*64 + ch*8);
    }
    if (t < 128) nrmS[t] = enrm[c*128 + t];
    __syncthreads();

    f32x4 acc2[4][2];
    #pragma unroll
    for (int fm = 0; fm < 4; ++fm)
      #pragma unroll
      for (int fn = 0; fn < 2; ++fn)
        #pragma unroll
        for (int q = 0; q < 4; ++q) acc2[fm][fn][q] = 0.f;

    #pragma unroll
    for (int ks = 0; ks < 2; ++ks) {
      bh8 ah[4], al[4];
      #pragma unroll
      for (int fm = 0; fm < 4; ++fm) {
        const int r = (fm*16 + lr)*72 + ks*32 + lg*8;
        ah[fm] = *(const bh8*)&Zh[r];
        al[fm] = *(const bh8*)&Zl[r];
      }
      #pragma unroll
      for (int fn = 0; fn < 2; ++fn) {
        const int r = (wv*32 + fn*16 + lr)*72 + ks*32 + lg*8;
        bh8 bh_ = *(const bh8*)&Eh[r];
        bh8 bl_ = *(const bh8*)&El[r];
        #pragma unroll
        for (int fm = 0; fm < 4; ++fm) {
          acc2[fm][fn] = __builtin_amdgcn_mfma_f32_16x16x32_bf16(ah[fm], bh_, acc2[fm][fn], 0,0,0);
          acc2[fm][fn] = __builtin_amdgcn_mfma_f32_16x16x32_bf16(al[fm], bh_, acc2[fm][fn], 0,0,0);
          acc2[fm][fn] = __builtin_amdgcn_mfma_f32_16x16x32_bf16(ah[fm], bl_, acc2[fm][fn], 0,0,0);
        }
      }
    }
    #pragma unroll
    for (int fn = 0; fn < 2; ++fn) {
      const int code = c*128 + wv*32 + fn*16 + lr;
      const float nv = nrmS[wv*32 + fn*16 + lr];
      #pragma unroll
      for (int fm = 0; fm < 4; ++fm)
        #pragma unroll
        for (int q = 0; q < 4; ++q) {
          float d = nv - 2.f*acc2[fm][fn][q];
          if (d < bv2[fm][q]) { bv2[fm][q] = d; bi2[fm][q] = code; }
        }
    }
  }

  #pragma unroll
  for (int fm = 0; fm < 4; ++fm)
    #pragma unroll
    for (int q = 0; q < 4; ++q) {
      float v = bv2[fm][q]; int ix = bi2[fm][q];
      #pragma unroll
      for (int m = 1; m < 16; m <<= 1) {
        float ov = __shfl_xor(v, m, 64);
        int   oi = __shfl_xor(ix, m, 64);
        if (ov < v || (ov == v && oi < ix)) { v = ov; ix = oi; }
      }
      if (lr == 0) {
        const int px = fm*16 + lg*4 + q;
        wredv[wv*64 + px] = v;
        wredi[wv*64 + px] = ix;
      }
    }
  __syncthreads();
  if (t < 64) {
    float best = 3.402823466e38f; int bid = 0x7fffffff;
    #pragma unroll
    for (int w2 = 0; w2 < 4; ++w2) {
      float v = wredv[w2*64 + t]; int ix = wredi[w2*64 + t];
      if (v < best || (v == best && ix < bid)) { best = v; bid = ix; }
    }
    sIdx[t] = bid;
  }
  __syncthreads();

  // ---- Phase 3: quantize (packed pairs) + loss + hist ----
  const int px = t & 63, grp = t >> 6;
  const int ix = sIdx[px];
  const float* er = emb + (size_t)ix * 64 + grp*16;
  uint* qb = qz32 + ((size_t)(n*32 + grp*8))*4096 + hwb + px;
  float ls = 0.f;
  #pragma unroll
  for (int dp = 0; dp < 8; ++dp) {
    float e0 = er[2*dp], e1 = er[2*dp + 1];
    float z0 = Zs[(grp*16 + 2*dp)*68 + px];
    float z1 = Zs[(grp*16 + 2*dp + 1)*68 + px];
    float d0 = e0 - z0, d1 = e1 - z1;
    ls += d0*d0 + d1*d1;
    qb[(size_t)dp * 4096] = (uint)f2bf(e0) | ((uint)f2bf(e1) << 16);
  }
  if (t < 64) atomicAdd(&hist[ix], 1);
  #pragma unroll
  for (int o = 32; o; o >>= 1) ls += __shfl_down(ls, o, 64);
  if ((t & 63) == 0) atomicAdd(loss_sum, ls);
}

__global__ void finalize_kernel(const int* __restrict__ hist,
                                const float* __restrict__ loss_sum,
                                float* __restrict__ out_loss,
                                float* __restrict__ out_perp) {
  __shared__ float red[512];
  int t = threadIdx.x;
  float pr = (float)hist[t] * (1.f/32768.f);
  red[t] = pr * logf(pr + 1e-10f);
  __syncthreads();
  for (int s = 256; s; s >>= 1) {
    if (t < s) red[t] += red[t + s];
    __syncthreads();
  }
  if (t == 0) {
    out_loss[0] = 1.25f * loss_sum[0] * (1.f/2097152.f);
    out_perp[0] = expf(-red[0]);
  }
}

// ===========================================================================
// DECODER postvq/deconv1: 128x128 tile, BK=64, bf16 MFMA (r14-r16, verified).
// ===========================================================================
enum { M_POSTVQ, M_DECONV1, M_DECONV2 };

template<int MODE>
__global__ __launch_bounds__(256, 4) void dec_mfma128(const uint* __restrict__ srcu,
                                                      const u16* __restrict__ Bt,
                                                      const float* __restrict__ bias,
                                                      uint* __restrict__ out32) {
  constexpr int K = (MODE == M_POSTVQ) ? 576 : 1024;
  __shared__ __align__(16) u16 As[128*72 + 32];
  __shared__ __align__(16) u16 Bs[128*72 + 32];

  const int t = threadIdx.x;
  int bid = xcd_swz((int)blockIdx.x, (int)gridDim.x);
  int par = 0, nt = 0, mt;
  if constexpr (MODE == M_DECONV1) { par = bid & 3; mt = bid >> 2; }
  else                             { nt = bid & 1;  mt = bid >> 1; }
  const u16* Brow = Bt + (size_t)((MODE == M_DECONV1) ? par*128 : nt*128) * K;

  const int pl = t & 127, kb = t >> 7;
  const int p = mt*128 + pl;
  const int n = p >> 12, h = (p >> 6) & 63, w = p & 63;
  const int lane = t & 63, wv = t >> 6;
  const int lr = lane & 15, lg = lane >> 4;
  const int wm = wv & 1, wn = wv >> 1;

  f32x4 acc[4][4];
  #pragma unroll
  for (int fm = 0; fm < 4; ++fm)
    #pragma unroll
    for (int fn = 0; fn < 4; ++fn)
      #pragma unroll
      for (int q = 0; q < 4; ++q) acc[fm][fn][q] = 0.f;

  const int aw = pl*72 + kb*32;

  for (int k0 = 0; k0 < K; k0 += 64) {
    const uint* up; bool ok;
    if constexpr (MODE == M_POSTVQ) {
      int r = k0 >> 6, kh = r / 3, kw = r - 3*kh;
      int ih = h - 1 + kh, iw = w - 1 + kw;
      ok = ((unsigned)ih < 64u) && ((unsigned)iw < 64u);
      up = srcu + ((size_t)(n*32 + kb*16)) * 4096
                + (ok ? ((ih << 6) + iw) : 0);
    } else {
      int j = k0 >> 8, icb = k0 & 255;
      int j1 = j >> 1, j0 = j & 1;
      int py = par >> 1, px = par & 1;
      int ih = h + py - 1 + j1, iw = w + px - 1 + j0;
      ok = ((unsigned)ih < 64u) && ((unsigned)iw < 64u);
      up = srcu + ((size_t)(n*128 + (icb >> 1) + kb*16)) * 4096
                + (ok ? ((ih << 6) + iw) : 0);
    }
    uint raw[16];
    #pragma unroll
    for (int i = 0; i < 16; ++i)
      raw[i] = ok ? up[(size_t)i * 4096] : 0u;

    __syncthreads();
    #pragma unroll
    for (int i = 0; i < 4; ++i)
      *(uint4*)&As[aw + i*8] =
          make_uint4(raw[4*i], raw[4*i+1], raw[4*i+2], raw[4*i+3]);

    #pragma unroll
    for (int i = 0; i < 4; ++i) {
      int id = i*256 + t, oc = id >> 3, ch = id & 7;
      *(uint4*)&Bs[oc*72 + ch*8] = *(const uint4*)(Brow + (size_t)oc*K + k0 + ch*8);
    }
    __syncthreads();

    #pragma unroll
    for (int ks = 0; ks < 2; ++ks) {
      bh8 af[4];
      #pragma unroll
      for (int fm = 0; fm < 4; ++fm)
        af[fm] = *(const bh8*)&As[(wm*64 + fm*16 + lr)*72 + ks*32 + lg*8];
      #pragma unroll
      for (int fn = 0; fn < 4; ++fn) {
        bh8 bf = *(const bh8*)&Bs[(wn*64 + fn*16 + lr)*72 + ks*32 + lg*8];
        #pragma unroll
        for (int fm = 0; fm < 4; ++fm)
          acc[fm][fn] = __builtin_amdgcn_mfma_f32_16x16x32_bf16(af[fm], bf, acc[fm][fn], 0, 0, 0);
      }
    }
  }

  const bool evn = !(lr & 1);
  #pragma unroll
  for (int fm = 0; fm < 4; ++fm) {
    const int pq = mt*128 + wm*64 + fm*16 + lg*4;
    const int nn = pq >> 12, hwq = pq & 4095;
    #pragma unroll
    for (int fn = 0; fn < 4; ++fn) {
      const int oc = nt*128 + wn*64 + fn*16 + lr;
      const float bvv = bias[oc];
      float v[4];
      #pragma unroll
      for (int q = 0; q < 4; ++q) {
        v[q] = acc[fm][fn][q] + bvv;
        if constexpr (MODE == M_DECONV1) v[q] = fmaxf(v[q], 0.f);
      }
      float pv[4];
      #pragma unroll
      for (int q = 0; q < 4; ++q) pv[q] = __shfl_xor(v[q], 1, 64);
      uint pk[4];
      #pragma unroll
      for (int q = 0; q < 4; ++q) {
        u16 a = f2bf(evn ? v[q] : pv[q]);
        u16 b = f2bf(evn ? pv[q] : v[q]);
        pk[q] = (uint)a | ((uint)b << 16);
      }
      size_t pbase;
      if constexpr (MODE == M_POSTVQ)
        pbase = ((size_t)(nn*128 + (oc >> 1))) * 4096 + hwq;
      else
        pbase = ((size_t)((nn*4 + par)*64 + (oc >> 1))) * 4096 + hwq;
      if (evn) *(uint2*)(out32 + pbase)     = make_uint2(pk[0], pk[1]);
      else     *(uint2*)(out32 + pbase + 2) = make_uint2(pk[2], pk[3]);
    }
  }
}

// ===========================================================================
// DECODER deconv2 (BN=16, verified r13-r16 path, unchanged)
// ===========================================================================
__global__ __launch_bounds__(256, 4) void deconv2_mfma(const uint* __restrict__ srcu,
                                                       const u16* __restrict__ Bt,
                                                       const float* __restrict__ bias,
                                                       float* __restrict__ outf) {
  constexpr int K = 512, BN = 16;
  __shared__ __align__(16) u16 As[128 * 72];
  __shared__ __align__(16) u16 Bs[BN * 72];

  const int t = threadIdx.x;
  int bid = xcd_swz((int)blockIdx.x, (int)gridDim.x);
  int par = bid & 3; bid >>= 2;
  const int mt = bid;
  const u16* Brow = Bt + (size_t)par * BN * K;

  const int pl = t & 127, kb = t >> 7;
  const int p = mt * 128 + pl;
  const int n = p >> 14, h = (p >> 7) & 127, w = p & 127;

  const int lane = t & 63, wv = t >> 6;
  const int lr = lane & 15, lg = lane >> 4;

  f32x4 acc[2];
  #pragma unroll
  for (int fm = 0; fm < 2; ++fm)
    #pragma unroll
    for (int q = 0; q < 4; ++q) acc[fm][q] = 0.f;

  for (int k0 = 0; k0 < K; k0 += 64) {
    int tap = k0 >> 7, icb = k0 & 127;
    int j1 = tap >> 1, j0 = tap & 1;
    int qy = par >> 1, qx = par & 1;
    int ih = h - 1 + qy + j1, iw = w - 1 + qx + j0;
    bool ok = ((unsigned)ih < 128u) && ((unsigned)iw < 128u);
    int ipar = ((ih & 1) << 1) | (iw & 1);
    const uint* up = srcu + ((size_t)((n*4 + ipar)*64 + (icb >> 1) + kb*16)) * 4096
                          + (ok ? (((ih >> 1) << 6) + (iw >> 1)) : 0);
    uint raw[16];
    #pragma unroll
    for (int i = 0; i < 16; ++i)
      raw[i] = ok ? up[(size_t)i * 4096] : 0u;

    __syncthreads();
    #pragma unroll
    for (int i = 0; i < 4; ++i)
      *(uint4*)&As[pl*72 + kb*32 + i*8] =
          make_uint4(raw[4*i], raw[4*i+1], raw[4*i+2], raw[4*i+3]);
    {
      int id = t;
      if (id < BN*8) {
        int oc = id >> 3, ch = id & 7;
        *(uint4*)&Bs[oc*72 + ch*8] = *(const uint4*)(Brow + (size_t)oc*K + k0 + ch*8);
      }
    }
    __syncthreads();

    #pragma unroll
    for (int ks = 0; ks < 2; ++ks) {
      bh8 af[2];
      #pragma unroll
      for (int fm = 0; fm < 2; ++fm)
        af[fm] = *(const bh8*)&As[(wv*32 + fm*16 + lr)*72 + ks*32 + lg*8];
      bh8 bf = *(const bh8*)&Bs[lr*72 + ks*32 + lg*8];
      #pragma unroll
      for (int fm = 0; fm < 2; ++fm)
        acc[fm] = __builtin_amdgcn_mfma_f32_16x16x32_bf16(af[fm], bf, acc[fm], 0, 0, 0);
    }
  }

  #pragma unroll
  for (int fm = 0; fm < 2; ++fm) {
    const int pq = mt*128 + wv*32 + fm*16 + lg*4;
    const int oc = lr;
    if (oc < 3) {
      const float bvv = bias[oc];
      const int nn = pq >> 14;
      const int hq = (pq >> 7) & 127, wq = pq & 127;
      const int qy = par >> 1, qx = par & 1;
      const int oh = 2*hq + qy;
      float* ob = outf + (((size_t)(nn*3 + oc)) << 16) + (oh << 8) + qx;
      ob[2*wq]     = acc[fm][0] + bvv;
      ob[2*wq + 2] = acc[fm][1] + bvv;
      ob[2*wq + 4] = acc[fm][2] + bvv;
      ob[2*wq + 6] = acc[fm][3] + bvv;
    }
  }
}

// ===========================================================================
// Single prep kernel: all weight transforms + hist/lsum zeroing
// ===========================================================================
__global__ void prep_all(const float* __restrict__ ew1, const float* __restrict__ ew2,
                         const float* __restrict__ pvw, const float* __restrict__ emb,
                         const float* __restrict__ qvw, const float* __restrict__ dw1,
                         const float* __restrict__ dw2,
                         u16* bt1h, u16* bt1l, u16* bt2h, u16* bt2l,
                         u16* btph, u16* btpl,
                         u16* Ebh, u16* Ebl, float* enrm,
                         u16* btq, u16* btd, u16* btd2,
                         int* hist, float* lsum) {
  int i = blockIdx.x * 256 + threadIdx.x;
  if (i < 8192) {                               // bt1h/l [oc 128][k 64], k=ic*16+r
    int oc = i >> 6, k = i & 63;
    float v = (k < 48) ? ew1[oc*48 + k] : 0.f;
    u16 hi = f2bf(v);
    bt1h[i] = hi;
    bt1l[i] = f2bf(v - bf2f(hi));
  } else if ((i -= 8192) < 524288) {            // bt2h/l [oc][k'=dy*512+ic*4+dx]
    int oc = i >> 11, k = i & 2047;
    int dy = k >> 9, ic = (k >> 2) & 127, dx = k & 3;
    float v = ew2[oc*2048 + ic*16 + dy*4 + dx];
    u16 hi = f2bf(v);
    bt2h[i] = hi;
    bt2l[i] = f2bf(v - bf2f(hi));
  } else if ((i -= 524288) < 16384) {           // btph/l [d 64][k 256] (pvw row-major)
    float v = pvw[i];
    u16 hi = f2bf(v);
    btph[i] = hi;
    btpl[i] = f2bf(v - bf2f(hi));
  } else if ((i -= 16384) < 32768) {            // Ebh/Ebl [code][d] bf16 hi/lo
    float v = emb[i];
    u16 hi = f2bf(v);
    Ebh[i] = hi;
    Ebl[i] = f2bf(v - bf2f(hi));
  } else if ((i -= 32768) < 512) {              // ||e||^2 fp32
    float s = 0.f;
    const float* er = emb + (size_t)i * 64;
    #pragma unroll
    for (int d = 0; d < 64; ++d) s += er[d]*er[d];
    enrm[i] = s;
  } else if ((i -= 512) < 147456) {             // btq [oc][k=r*64+ic]
    int oc = i / 576, rem = i - oc*576, r = rem >> 6, ic = rem & 63;
    btq[i] = f2bf(qvw[oc*576 + ic*9 + r]);
  } else if ((i -= 147456) < 524288) {          // btd [par][oc][k=j*256+ic]
    int pr = i >> 17, oc = (i >> 10) & 127, j = (i >> 8) & 3, ic = i & 255;
    int py = pr >> 1, px = pr & 1, j1 = j >> 1, j0 = j & 1;
    btd[i] = f2bf(dw1[oc*4096 + ic*16 + (py + 2*j1)*4 + (px + 2*j0)]);
  } else if ((i -= 524288) < 32768) {           // btd2 [q][oc16][k=tap*128+ic]
    int q = i >> 13, oc = (i >> 9) & 15, tap = (i >> 7) & 3, ic = i & 127;
    int qy = q >> 1, qx = q & 1, j1 = tap >> 1, j0 = tap & 1;
    btd2[i] = (oc < 3) ? f2bf(dw2[oc*2048 + ic*16 + (qy + 2*j1)*4 + (qx + 2*j0)]) : (u16)0;
  } else if ((i -= 32768) < 528) {              // zero hist (512) + lsum (16 f)
    if (i < 512) hist[i] = 0;
    else         lsum[i - 512] = 0.f;
  }
}

// ===========================================================================
extern "C" void kernel_launch(void* const* d_in, const int* in_sizes, int n_in,
                              void* d_out, int out_size, void* d_ws, size_t ws_size,
                              hipStream_t stream) {
  (void)in_sizes; (void)n_in; (void)ws_size;
  const float* x   = (const float*)d_in[0];
  const float* ew1 = (const float*)d_in[1];
  const float* eb1 = (const float*)d_in[2];
  const float* ew2 = (const float*)d_in[3];
  const float* eb2 = (const float*)d_in[4];
  const float* pvw = (const float*)d_in[5];
  const float* pvb = (const float*)d_in[6];
  const float* emb = (const float*)d_in[7];
  const float* qvw = (const float*)d_in[8];
  const float* qvb = (const float*)d_in[9];
  const float* dw1 = (const float*)d_in[10];
  const float* db1 = (const float*)d_in[11];
  const float* dw2 = (const float*)d_in[12];
  const float* db2 = (const float*)d_in[13];
  float* out = (float*)d_out;

  char* ws = (char*)d_ws;
  uint*  h1u  = (uint*) (ws);                    // packed hi/lo parity planes, 67108864 B
  uint*  h2u  = (uint*) (ws + 67108864);         // [8*256][4096] packed hi/lo, 33554432 B
  uint*  qz32 = (uint*) (ws + 109051904);        // [8][32 c2][4096] packed, 4194304 B
  int*   hist = (int*)  (ws + 113246208);        // 2048 B
  float* lsum = (float*)(ws + 113248256);        // 64 B
  u16*   bt1h = (u16*)  (ws + 113248320);        // 16384 B
  u16*   bt1l = (u16*)  (ws + 113264704);        // 16384 B
  u16*   btph = (u16*)  (ws + 113281088);        // 32768 B
  u16*   btpl = (u16*)  (ws + 113313856);        // 32768 B
  u16*   bt2h = (u16*)  (ws + 113346624);        // 1048576 B
  u16*   bt2l = (u16*)  (ws + 114395200);        // 1048576 B
  u16*   btq  = (u16*)  (ws + 115443776);        // 294912 B
  u16*   btd  = (u16*)  (ws + 115738688);        // 1048576 B
  u16*   btd2 = (u16*)  (ws + 116787264);        // 65536 B
  u16*   Ebh  = (u16*)  (ws + 116852800);        // 65536 B
  u16*   Ebl  = (u16*)  (ws + 116918336);        // 65536 B
  float* enrm = (float*)(ws + 116983872);        // 2048 B
  uint* g32  = (uint*)(ws + 67108864);  // [8][128 c2][4096] packed, overlays h2u (dead)
  uint* g232 = (uint*)ws;               // [8][4 par][64 c2][4096] packed, overlays h1u

  prep_all<<<5029, 256, 0, stream>>>(ew1, ew2, pvw, emb, qvw, dw1, dw2,
                                     bt1h, bt1l, bt2h, bt2l, btph, btpl,
                                     Ebh, Ebl, enrm, btq, btd, btd2, hist, lsum);

  conv1_mfma3<<<1024, 256, 0, stream>>>(x, bt1h, bt1l, eb1, h1u);
  conv2_mfma3<<<512, 256, 0, stream>>>(h1u, bt2h, bt2l, eb2, h2u);

  prevq_vq<<<512, 256, 0, stream>>>(h2u, btph, btpl, pvb, emb, Ebh, Ebl, enrm,
                                    qz32, hist, lsum);
  finalize_kernel<<<1, 512, 0, stream>>>(hist, lsum, out, out + (out_size - 1));

  dec_mfma128<M_POSTVQ> <<<512,  256, 0, stream>>>(qz32, btq, qvb, g32);
  dec_mfma128<M_DECONV1><<<1024, 256, 0, stream>>>(g32, btd, db1, g232);
  deconv2_mfma<<<4096, 256, 0, stream>>>(g232, btd2, db2, out + 1);
}